// Round 9
// baseline (3759.524 us; speedup 1.0000x reference)
//
#include <hip/hip_runtime.h>

typedef _Float16 half8 __attribute__((ext_vector_type(8)));
typedef float floatx4 __attribute__((ext_vector_type(4)));
typedef unsigned int u32x4 __attribute__((ext_vector_type(4)));
typedef unsigned int u32x2 __attribute__((ext_vector_type(2)));
typedef unsigned long long u64;
typedef unsigned int u32;
typedef unsigned short u16;

#define T_LEN 16384
#define DM 512
#define NC 2048      // 4*DM
#define NG 16        // groups
#define NR 16        // segment rows (batch) per group
#define WPG 16       // workgroups per group
// H exchange: per group per parity, 4096 granules x 8B = 32KB.
// granule = { u32 data (2 f16), u32 tag } — 8B naturally aligned => single-copy
// atomic (LLVM AMDGPU memory model: only accesses <=64b are atomic; R8's 16B
// chunks tore, tag arrived without data).
#define HBYTES (4096 * 8)

struct Meta { int S; int use_h0; int steps_g[NG]; };

union FragU { u64 q[2]; u32x4 r; half8 v; };

__device__ __forceinline__ float sigf(float x) { return 1.0f / (1.0f + __expf(-x)); }
__device__ __forceinline__ float tanh_f(float x) { return 1.0f - 2.0f / (__expf(2.0f * x) + 1.0f); }

// ---------------- zero workspace region ----------------
__global__ void zero_kernel(u32* __restrict__ p, size_t nwords) {
    size_t i = (size_t)blockIdx.x * blockDim.x + threadIdx.x;
    size_t stride = (size_t)gridDim.x * blockDim.x;
    for (; i < nwords; i += stride) p[i] = 0u;
}

// ---------------- f32 -> f16 pack (row-major) ----------------
__global__ void pack_f16_kernel(const float* __restrict__ src, _Float16* __restrict__ dst, int n8) {
    int i = blockIdx.x * blockDim.x + threadIdx.x;
    if (i >= n8) return;
    const floatx4* s = (const floatx4*)src + (size_t)i * 2;
    floatx4 a = s[0], b = s[1];
    half8 o;
    o[0] = (_Float16)a[0]; o[1] = (_Float16)a[1]; o[2] = (_Float16)a[2]; o[3] = (_Float16)a[3];
    o[4] = (_Float16)b[0]; o[5] = (_Float16)b[1]; o[6] = (_Float16)b[2]; o[7] = (_Float16)b[3];
    ((half8*)dst)[i] = o;
}

// ---------------- weight pack to MFMA B-fragment order ----------------
__global__ __launch_bounds__(256) void pack_w_kernel(const float* __restrict__ src, half8* __restrict__ dst) {
    int wid = blockIdx.x * 4 + (threadIdx.x >> 6);  // 2048 = 128 tiles * 16 kt
    int l = threadIdx.x & 63;
    int tt = wid >> 4, kt = wid & 15;
    int q = tt & 3, cch = tt >> 2;
    int col = q * 512 + cch * 16 + (l & 15);
    int h = l >> 4;
    half8 o;
#pragma unroll
    for (int jj = 0; jj < 8; jj++) o[jj] = (_Float16)src[(size_t)(kt * 32 + h * 8 + jj) * NC + col];
    dst[(tt * 16 + kt) * 64 + l] = o;
}

// ---------------- prep: term dtype detect, segment extraction, chains ----------------
__global__ void prep_kernel(const void* __restrict__ termraw, const float* __restrict__ h0,
                            int* __restrict__ seg_start, int* __restrict__ seg_len,
                            Meta* __restrict__ meta, _Float16* __restrict__ Hbuf) {
    __shared__ int cnts[256], offs[256];
    __shared__ int nzm, oddnz, totS;
    __shared__ int chain[256];
    int tid = threadIdx.x;
    if (tid == 0) { nzm = 0; oddnz = 0; }
    __syncthreads();
    const unsigned char* tb = (const unsigned char*)termraw;
    const int* ti = (const int*)termraw;
    int lm = 0;
    for (int i = tid; i < T_LEN; i += 256) {
        if (tb[i]) {
            int p = i & 3;
            if (p == 1 || p == 2) lm |= 1;
            else if (p == 3) lm |= 2;
            else lm |= 4;
        }
    }
    if (lm) atomicOr(&nzm, lm);
    __syncthreads();
    int mm = nzm;
    int bytemode = (mm & 1) ? 1 : 0;
    int floatmode = (!bytemode && (mm & 2)) ? 1 : 0;
    int lo = 0;
    if (!bytemode && !floatmode) {
        for (int k2 = 2 * tid + 1; k2 < T_LEN; k2 += 512) if (ti[k2]) lo = 1;
    }
    if (lo) atomicOr(&oddnz, 1);
    __syncthreads();
    int i64mode = (!bytemode && !floatmode && oddnz == 0 && (mm & 4)) ? 1 : 0;
    const float* tf = (const float*)termraw;

    auto termAt = [&](int t) -> int {
        if (bytemode) return tb[t] != 0;
        if (floatmode) return tf[t] != 0.0f;
        if (i64mode) return (ti[2 * t] != 0) || (ti[2 * t + 1] != 0);
        return ti[t] != 0;
    };

    int base = tid * 64;
    int cnt = 0;
    for (int k = 0; k < 64; k++) {
        int t = base + k;
        if (t == 0 || termAt(t)) cnt++;
    }
    cnts[tid] = cnt;
    __syncthreads();
    if (tid == 0) {
        int a = 0;
        for (int i = 0; i < 256; i++) { offs[i] = a; a += cnts[i]; }
        totS = a;
        meta->S = a;
    }
    __syncthreads();
    int S = totS;
    {
        int o = offs[tid];
        for (int k = 0; k < 64; k++) {
            int t = base + k;
            if (t == 0 || termAt(t)) seg_start[o++] = t;
        }
    }
    __syncthreads();
    for (int i = tid; i < S; i += 256)
        seg_len[i] = ((i + 1 < S) ? seg_start[i + 1] : T_LEN) - seg_start[i];
    __syncthreads();
    {
        int g = tid >> 4, r = tid & 15;
        int tot = 0;
        for (int i = g + 16 * r; i < S; i += 256) tot += seg_len[i];
        chain[tid] = tot;
    }
    __syncthreads();
    if (tid < NG) {
        int mx = 0;
        for (int r = 0; r < 16; r++) mx = max(mx, chain[tid * 16 + r]);
        meta->steps_g[tid] = mx;
    }
    int u = termAt(0);
    if (tid == 0) meta->use_h0 = !u;
    if (!u) {
        // h0 seed: group0/parity0/row0, granule layout; tags stay 0 (zeroed).
        for (int d2 = tid; d2 < DM; d2 += 256) {
            int v8chunk = ((d2 >> 5) * 64 + ((d2 >> 3) & 3) * 16) * 2 + ((d2 >> 2) & 1);
            int c8 = v8chunk * 2 + ((d2 >> 1) & 1);
            Hbuf[c8 * 4 + (d2 & 1)] = (_Float16)h0[d2];
        }
    }
}

// ---------------- XW = inputs @ Wx + b (fp16 MFMA, packed-col order, fp16 out) ----------------
__global__ __launch_bounds__(256) void xw_gemm_kernel(const half8* __restrict__ A, const half8* __restrict__ B,
                                                      const float* __restrict__ bias, _Float16* __restrict__ XW) {
    int bx = blockIdx.x, by = blockIdx.y;
    int w = threadIdx.x >> 6, l = threadIdx.x & 63;
    int mbase = bx * 64 + w * 16;
    int h = l >> 4, n = l & 15;
    floatx4 acc[8] = {};
    int arow = mbase + n;
#pragma unroll
    for (int kt = 0; kt < 16; kt++) {
        half8 a = A[(size_t)arow * 64 + kt * 4 + h];
#pragma unroll
        for (int nt = 0; nt < 8; nt++)
            acc[nt] = __builtin_amdgcn_mfma_f32_16x16x32_f16(a, B[((by * 8 + nt) * 16 + kt) * 64 + l], acc[nt], 0, 0, 0);
    }
#pragma unroll
    for (int nt = 0; nt < 8; nt++) {
        int tt = by * 8 + nt, q = tt & 3, cch = tt >> 2;
        float bv = bias[q * 512 + cch * 16 + n];
#pragma unroll
        for (int r = 0; r < 4; r++) {
            int row = mbase + h * 4 + r;
            XW[(size_t)row * NC + tt * 16 + n] = (_Float16)(acc[nt][r] + bv);
        }
    }
}

// ---------------- per-thread segment tracker ----------------
struct Trk { int seg, t0, s0, end, active; };

__device__ __forceinline__ void trk_init(Trk& k, int row, int g, int S,
                                         const int* __restrict__ ss, const int* __restrict__ sl) {
    int seg = g + 16 * row;
    k.seg = seg;
    if (seg < S) { k.t0 = ss[seg]; k.s0 = 0; k.end = sl[seg]; k.active = 1; }
    else { k.t0 = 0; k.s0 = 0; k.end = 0x7fffffff; k.active = 0; }
}

__device__ __forceinline__ int trk_step(Trk& k, int s, int S,
                                        const int* __restrict__ ss, const int* __restrict__ sl, int& t_out) {
    int z = !k.active;
    if (s > 0 && k.active && s == k.end) {
        int seg = k.seg + 256;
        if (seg < S) { k.seg = seg; k.t0 = ss[seg]; k.s0 = s; k.end = s + sl[seg]; z = 1; }
        else { k.active = 0; z = 1; }
    }
    t_out = k.active ? (k.t0 + (s - k.s0)) : 0;
    return z;
}

// ---------------- recurrent scan v9: tag-embedded exchange, 8B-atomic granules ----------------
// Producer: TWO dwordx2 sc1 stores per lane ({2 f16, tag} each; 8B single-copy atomic,
// self-validating). No drain, no flag. Consumer: poll-burst of 64 dwordx2 loads;
// every granule's tag validates its own 4B of data in the SAME load.
__global__ __launch_bounds__(192, 1) void scan_kernel(
    const half8* __restrict__ PW, const _Float16* __restrict__ XW,
    const float* __restrict__ c0,
    const int* __restrict__ seg_start, const int* __restrict__ seg_len,
    const Meta* __restrict__ meta,
    char* __restrict__ Hbuf, float* __restrict__ out) {
    const int b = blockIdx.x;
    const int g = (b & 7) * 2 + (b >> 7);   // XCD-local groups (perf hint only)
    const int jj = (b >> 3) & 15;
    const int tid = threadIdx.x;
    const int w = tid >> 6, l = tid & 63;
    const int S = meta->S;
    const int steps = meta->steps_g[g];
    if (steps <= 0) return;
    const int use_h0 = meta->use_h0;

    __shared__ __align__(16) u16 hstage[2][NR][16];
    __shared__ __align__(16) _Float16 xwstage[2][NR][128];   // [buf][row][WG's 128 packed cols]
    __shared__ __align__(16) float outstage[2][2][NR][32];   // [buf][h|c][row][WG's 32 dims]
    __shared__ __align__(16) half8 whlds[2][2][16][64];      // [wave][gate-2][kt][lane], 64KB
    __shared__ int ioflag[2];
    __shared__ int outcnt[2];

    if (tid == 0) { ioflag[0] = -1; ioflag[1] = -1; outcnt[0] = 0; outcnt[1] = 0; }
    // stage Wh gates g,o into LDS (compute waves only; init phase)
    if (w < 2) {
        const int c0i = jj * 2 + w;
#pragma unroll
        for (int kt = 0; kt < 16; kt++)
#pragma unroll
            for (int qq = 0; qq < 2; qq++)
                whlds[w][qq][kt][l] = PW[((c0i * 4 + 2 + qq) * 16 + kt) * 64 + l];
    }
    __syncthreads();

    float* outH = out;
    float* outC = out + (size_t)T_LEN * DM;
    float* outH2 = out + 2 * (size_t)T_LEN * DM;

    if (w < 2) {
        // ================= COMPUTE WAVE =================
        const int c = jj * 2 + w;               // dim chunk 0..31 (16 dims each)
        const int n = l & 15, h = l >> 4;
        const int d = c * 16 + n;
        const int m = n;

        // resident Wh B-fragments for gates i,f (128 VGPR)
        half8 bfv[2][16];
#pragma unroll
        for (int q = 0; q < 2; q++)
#pragma unroll
            for (int kt = 0; kt < 16; kt++) {
                bfv[q][kt] = PW[((c * 4 + q) * 16 + kt) * 64 + l];
                asm volatile("" : "+v"(bfv[q][kt]));
            }

        Trk trkM; trk_init(trkM, n, g, S, seg_start, seg_len);
        Trk trk[4];
#pragma unroll
        for (int r = 0; r < 4; r++) trk_init(trk[r], h * 4 + r, g, S, seg_start, seg_len);

        float cc[4];
#pragma unroll
        for (int r = 0; r < 4; r++) {
            int row = h * 4 + r;
            cc[r] = (g == 0 && row == 0 && use_h0) ? c0[d] : 0.0f;
        }

        FragU zu; zu.q[0] = 0; zu.q[1] = 0;
        const half8 zfrag = zu.v;

        // producer granule coords (v8chunk = former u64 index; 2 granules per chunk)
        const int b2 = l >> 5, m2 = (l >> 1) & 15, half = l & 1;
        const int ktc = c >> 1, hhp = (c & 1) * 2 + b2;
        const int ldsIdx = m2 * 4 + b2 * 2 + half;
        const int v8chunk = (ktc * 4 + hhp) * 32 + m2 * 2 + half;

        for (int s = 0; s < steps; ++s) {
            // ---- trackers for step s ----
            int tdump;
            const int zM = trk_step(trkM, s, S, seg_start, seg_len, tdump);
            int zz[4];
#pragma unroll
            for (int r = 0; r < 4; r++)
                zz[r] = trk_step(trk[r], s, S, seg_start, seg_len, tdump);

            // ---- XW(s) from LDS stage (pre-staged by IO wave) ----
            while (__hip_atomic_load(&ioflag[s & 1], __ATOMIC_RELAXED, __HIP_MEMORY_SCOPE_WORKGROUP) < s)
                __builtin_amdgcn_s_sleep(1);
            asm volatile("" ::: "memory");
            float xwv[4][4];
#pragma unroll
            for (int q = 0; q < 4; q++)
#pragma unroll
                for (int r = 0; r < 4; r++)
                    xwv[q][r] = (float)xwstage[s & 1][h * 4 + r][w * 64 + q * 16 + n];

            // ---- poll-burst: 64 x dwordx2, every 8B granule self-validating ----
            const char* Hrb = Hbuf + (size_t)(g * 2 + (s & 1)) * HBYTES;
            const char* p0 = Hrb + ((h * 16 + m) << 5);
            u32x2 raw[64];
            while (true) {
#pragma unroll
                for (int kt = 0; kt < 16; kt++) {
                    const char* ap = p0 + (kt << 11);
                    asm volatile("global_load_dwordx2 %0, %1, off sc1" : "=v"(raw[4 * kt]) : "v"(ap) : "memory");
                    asm volatile("global_load_dwordx2 %0, %1, off offset:8 sc1" : "=v"(raw[4 * kt + 1]) : "v"(ap) : "memory");
                    asm volatile("global_load_dwordx2 %0, %1, off offset:16 sc1" : "=v"(raw[4 * kt + 2]) : "v"(ap) : "memory");
                    asm volatile("global_load_dwordx2 %0, %1, off offset:24 sc1" : "=v"(raw[4 * kt + 3]) : "v"(ap) : "memory");
                }
                asm volatile("s_waitcnt vmcnt(0)" ::: "memory");
                __builtin_amdgcn_sched_barrier(0);
                u32 bad = 0;
#pragma unroll
                for (int kt = 0; kt < 16; kt++)
                    bad |= (raw[4 * kt][1] ^ (u32)s) | (raw[4 * kt + 1][1] ^ (u32)s)
                         | (raw[4 * kt + 2][1] ^ (u32)s) | (raw[4 * kt + 3][1] ^ (u32)s);
                if (__all(bad == 0)) break;
                __builtin_amdgcn_s_sleep(1);
            }
            half8 afr[16];
#pragma unroll
            for (int kt = 0; kt < 16; kt++) {
                FragU u;
                u.r[0] = raw[4 * kt][0];
                u.r[1] = raw[4 * kt + 1][0];
                u.r[2] = raw[4 * kt + 2][0];
                u.r[3] = raw[4 * kt + 3][0];
                afr[kt] = zM ? zfrag : u.v;
            }

            // ---- MFMA: gates i,f from VGPR; g,o from LDS (lgkm, hidden) ----
            floatx4 acc[4] = {};
#pragma unroll
            for (int kt = 0; kt < 16; kt++) {
                acc[0] = __builtin_amdgcn_mfma_f32_16x16x32_f16(afr[kt], bfv[0][kt], acc[0], 0, 0, 0);
                acc[1] = __builtin_amdgcn_mfma_f32_16x16x32_f16(afr[kt], bfv[1][kt], acc[1], 0, 0, 0);
                acc[2] = __builtin_amdgcn_mfma_f32_16x16x32_f16(afr[kt], whlds[w][0][kt][l], acc[2], 0, 0, 0);
                acc[3] = __builtin_amdgcn_mfma_f32_16x16x32_f16(afr[kt], whlds[w][1][kt][l], acc[3], 0, 0, 0);
            }

            float hnv[4], cnv[4];
#pragma unroll
            for (int r = 0; r < 4; r++) {
                float zi = acc[0][r] + xwv[0][r];
                float zf = acc[1][r] + xwv[1][r];
                float zg = acc[2][r] + xwv[2][r];
                float zo = acc[3][r] + xwv[3][r];
                float cprev = zz[r] ? 0.0f : cc[r];
                float cn = sigf(zf) * cprev + sigf(zi) * tanh_f(zg);
                float hn = sigf(zo) * tanh_f(cn);
                cc[r] = cn; hnv[r] = hn; cnv[r] = cn;
                hstage[w][h * 4 + r][n] = __builtin_bit_cast(u16, (_Float16)hn);
            }

            // wave-local regroup via LDS; order u16-writes -> u64-read (R3 lesson)
            asm volatile("s_waitcnt lgkmcnt(0)" ::: "memory");
            __builtin_amdgcn_sched_barrier(0);
            u64 pk = ((const u64*)&hstage[w][0][0])[ldsIdx];

            // ---- publish: TWO dwordx2 = {2 f16, tag} each. Atomic granules. ----
            char* Hwb = Hbuf + (size_t)(g * 2 + ((s & 1) ^ 1)) * HBYTES;
            u32 tag = (u32)(s + 1);
            u32x2 stA, stB;
            stA[0] = (u32)pk;         stA[1] = tag;
            stB[0] = (u32)(pk >> 32); stB[1] = tag;
            char* hwp = Hwb + ((size_t)v8chunk << 4);
            asm volatile("global_store_dwordx2 %0, %1, off sc1" :: "v"(hwp), "v"(stA) : "memory");
            asm volatile("global_store_dwordx2 %0, %1, off offset:8 sc1" :: "v"(hwp), "v"(stB) : "memory");

            // ---- hand outputs to IO wave via LDS ----
            while (__hip_atomic_load(&outcnt[s & 1], __ATOMIC_RELAXED, __HIP_MEMORY_SCOPE_WORKGROUP) == 2)
                __builtin_amdgcn_s_sleep(1);
            asm volatile("" ::: "memory");
#pragma unroll
            for (int r = 0; r < 4; r++) {
                outstage[s & 1][0][h * 4 + r][w * 16 + n] = hnv[r];
                outstage[s & 1][1][h * 4 + r][w * 16 + n] = cnv[r];
            }
            asm volatile("s_waitcnt lgkmcnt(0)" ::: "memory");
            if (l == 0)
                __hip_atomic_fetch_add(&outcnt[s & 1], 1, __ATOMIC_RELAXED, __HIP_MEMORY_SCOPE_WORKGROUP);
        }
    } else {
        // ================= IO WAVE =================
        const int rX = l >> 4;
        const int rO = l >> 3;
        Trk trkX[4];
#pragma unroll
        for (int i = 0; i < 4; i++) trk_init(trkX[i], rX + 4 * i, g, S, seg_start, seg_len);
        Trk trkO[2];
        trk_init(trkO[0], rO, g, S, seg_start, seg_len);
        trk_init(trkO[1], rO + 8, g, S, seg_start, seg_len);

        auto stageXW = [&](int step, int buf) {
            int tX[4];
#pragma unroll
            for (int i = 0; i < 4; i++) (void)trk_step(trkX[i], step, S, seg_start, seg_len, tX[i]);
            u32x4 xr[4];
#pragma unroll
            for (int i = 0; i < 4; i++)
                xr[i] = *(const u32x4*)((const char*)XW + ((size_t)tX[i] * NC + jj * 128 + (l & 15) * 8) * 2);
#pragma unroll
            for (int i = 0; i < 4; i++)
                *(u32x4*)&xwstage[buf][rX + 4 * i][(l & 15) * 8] = xr[i];
            asm volatile("s_waitcnt lgkmcnt(0)" ::: "memory");
            if (l == 0)
                __hip_atomic_store(&ioflag[buf], step, __ATOMIC_RELAXED, __HIP_MEMORY_SCOPE_WORKGROUP);
        };

        stageXW(0, 0);
        stageXW(1, 1);

        for (int s = 0; s < steps; ++s) {
            int tO[2], aO[2];
#pragma unroll
            for (int j2 = 0; j2 < 2; j2++) {
                (void)trk_step(trkO[j2], s, S, seg_start, seg_len, tO[j2]);
                aO[j2] = trkO[j2].active;
            }
            while (__hip_atomic_load(&outcnt[s & 1], __ATOMIC_RELAXED, __HIP_MEMORY_SCOPE_WORKGROUP) < 2)
                __builtin_amdgcn_s_sleep(1);
            asm volatile("" ::: "memory");
            floatx4 hv[2], cv[2];
#pragma unroll
            for (int j2 = 0; j2 < 2; j2++) {
                hv[j2] = *(floatx4*)&outstage[s & 1][0][rO + 8 * j2][(l & 7) * 4];
                cv[j2] = *(floatx4*)&outstage[s & 1][1][rO + 8 * j2][(l & 7) * 4];
            }
            asm volatile("s_waitcnt lgkmcnt(0)" ::: "memory");
            __hip_atomic_store(&outcnt[s & 1], 0, __ATOMIC_RELAXED, __HIP_MEMORY_SCOPE_WORKGROUP);
#pragma unroll
            for (int j2 = 0; j2 < 2; j2++) {
                if (aO[j2]) {
                    size_t base = (size_t)tO[j2] * DM + jj * 32 + (l & 7) * 4;
                    *(floatx4*)&outH[base] = hv[j2];
                    *(floatx4*)&outC[base] = cv[j2];
                    *(floatx4*)&outH2[base] = hv[j2];
                }
            }
            stageXW(s + 2, s & 1);
        }
    }
}

extern "C" void kernel_launch(void* const* d_in, const int* in_sizes, int n_in,
                              void* d_out, int out_size, void* d_ws, size_t ws_size,
                              hipStream_t stream) {
    const float* inputs = (const float*)d_in[0];
    const void* terms = d_in[1];
    const float* c0 = (const float*)d_in[2];
    const float* h0 = (const float*)d_in[3];
    const float* Wx = (const float*)d_in[4];
    const float* Wh = (const float*)d_in[5];
    const float* bias = (const float*)d_in[6];
    float* out = (float*)d_out;

    size_t off = 0;
    auto take = [&](size_t bts) { size_t cur = off; off = (off + bts + 255) & ~(size_t)255; return cur; };
    size_t offXW = take((size_t)T_LEN * NC * 2);       // fp16 XW
    size_t offAin = take((size_t)T_LEN * DM * 2);
    size_t offPX = take((size_t)DM * NC * 2);
    size_t offPW = take((size_t)DM * NC * 2);
    size_t offSS = take((size_t)(T_LEN + 2) * 4);
    size_t offSL = take((size_t)(T_LEN + 2) * 4);
    size_t offH = take(2ull * NG * HBYTES);            // granule H buffers (1MB)
    size_t offME = take(256);
    size_t total = off;
    (void)ws_size;

    char* W = (char*)d_ws;
    _Float16* Ain = (_Float16*)(W + offAin);
    half8* PX = (half8*)(W + offPX);
    half8* PWp = (half8*)(W + offPW);
    int* segS = (int*)(W + offSS);
    int* segL = (int*)(W + offSL);
    Meta* meta = (Meta*)(W + offME);
    _Float16* XWp = (_Float16*)(W + offXW);

    size_t zwords = (total - offH) / 4;  // Hbuf + meta contiguous
    zero_kernel<<<256, 256, 0, stream>>>((u32*)(W + offH), zwords);
    pack_f16_kernel<<<(T_LEN * DM / 8 + 255) / 256, 256, 0, stream>>>(inputs, Ain, T_LEN * DM / 8);
    pack_w_kernel<<<512, 256, 0, stream>>>(Wx, PX);
    pack_w_kernel<<<512, 256, 0, stream>>>(Wh, PWp);
    prep_kernel<<<1, 256, 0, stream>>>(terms, h0, segS, segL, meta, (_Float16*)(W + offH));

    dim3 gg(T_LEN / 64, NC / 128);
    xw_gemm_kernel<<<gg, 256, 0, stream>>>((const half8*)Ain, (const half8*)PX, bias, XWp);
    scan_kernel<<<256, 192, 0, stream>>>((const half8*)PWp, XWp, c0, segS, segL, meta,
                                         (char*)(W + offH), out);
}

// Round 10
// 2215.265 us; speedup vs baseline: 1.6971x; 1.6971x over previous
//
#include <hip/hip_runtime.h>

typedef _Float16 half8 __attribute__((ext_vector_type(8)));
typedef float floatx4 __attribute__((ext_vector_type(4)));
typedef unsigned int u32x4 __attribute__((ext_vector_type(4)));
typedef unsigned long long u64;
typedef unsigned int u32;
typedef unsigned short u16;

#define T_LEN 16384
#define DM 512
#define NC 2048      // 4*DM
#define NG 16        // groups
#define NR 16        // segment rows (batch) per group
#define WPG 16       // workgroups per group
#define WVG 32       // compute waves per group (= flags per group)
#define PROBE_ROUNDS 12
#define PROBE_CAP 4000

struct Meta { int S; int use_h0; int steps_g[NG]; };

union FragU { u64 q[2]; u32x4 r; half8 v; };

__device__ __forceinline__ float sigf(float x) { return 1.0f / (1.0f + __expf(-x)); }
__device__ __forceinline__ float tanh_f(float x) { return 1.0f - 2.0f / (__expf(2.0f * x) + 1.0f); }

// ---------------- zero workspace region ----------------
__global__ void zero_kernel(u32* __restrict__ p, size_t nwords) {
    size_t i = (size_t)blockIdx.x * blockDim.x + threadIdx.x;
    size_t stride = (size_t)gridDim.x * blockDim.x;
    for (; i < nwords; i += stride) p[i] = 0u;
}

// ---------------- f32 -> f16 pack (row-major) ----------------
__global__ void pack_f16_kernel(const float* __restrict__ src, _Float16* __restrict__ dst, int n8) {
    int i = blockIdx.x * blockDim.x + threadIdx.x;
    if (i >= n8) return;
    const floatx4* s = (const floatx4*)src + (size_t)i * 2;
    floatx4 a = s[0], b = s[1];
    half8 o;
    o[0] = (_Float16)a[0]; o[1] = (_Float16)a[1]; o[2] = (_Float16)a[2]; o[3] = (_Float16)a[3];
    o[4] = (_Float16)b[0]; o[5] = (_Float16)b[1]; o[6] = (_Float16)b[2]; o[7] = (_Float16)b[3];
    ((half8*)dst)[i] = o;
}

// ---------------- weight pack to MFMA B-fragment order ----------------
__global__ __launch_bounds__(256) void pack_w_kernel(const float* __restrict__ src, half8* __restrict__ dst) {
    int wid = blockIdx.x * 4 + (threadIdx.x >> 6);  // 2048 = 128 tiles * 16 kt
    int l = threadIdx.x & 63;
    int tt = wid >> 4, kt = wid & 15;
    int q = tt & 3, cch = tt >> 2;
    int col = q * 512 + cch * 16 + (l & 15);
    int h = l >> 4;
    half8 o;
#pragma unroll
    for (int jj = 0; jj < 8; jj++) o[jj] = (_Float16)src[(size_t)(kt * 32 + h * 8 + jj) * NC + col];
    dst[(tt * 16 + kt) * 64 + l] = o;
}

// ---------------- prep: term dtype detect, segment extraction, chains ----------------
__global__ void prep_kernel(const void* __restrict__ termraw, const float* __restrict__ h0,
                            int* __restrict__ seg_start, int* __restrict__ seg_len,
                            Meta* __restrict__ meta, _Float16* __restrict__ Hbuf) {
    __shared__ int cnts[256], offs[256];
    __shared__ int nzm, oddnz, totS;
    __shared__ int chain[256];
    int tid = threadIdx.x;
    if (tid == 0) { nzm = 0; oddnz = 0; }
    __syncthreads();
    const unsigned char* tb = (const unsigned char*)termraw;
    const int* ti = (const int*)termraw;
    int lm = 0;
    for (int i = tid; i < T_LEN; i += 256) {
        if (tb[i]) {
            int p = i & 3;
            if (p == 1 || p == 2) lm |= 1;
            else if (p == 3) lm |= 2;
            else lm |= 4;
        }
    }
    if (lm) atomicOr(&nzm, lm);
    __syncthreads();
    int mm = nzm;
    int bytemode = (mm & 1) ? 1 : 0;
    int floatmode = (!bytemode && (mm & 2)) ? 1 : 0;
    int lo = 0;
    if (!bytemode && !floatmode) {
        for (int k2 = 2 * tid + 1; k2 < T_LEN; k2 += 512) if (ti[k2]) lo = 1;
    }
    if (lo) atomicOr(&oddnz, 1);
    __syncthreads();
    int i64mode = (!bytemode && !floatmode && oddnz == 0 && (mm & 4)) ? 1 : 0;
    const float* tf = (const float*)termraw;

    auto termAt = [&](int t) -> int {
        if (bytemode) return tb[t] != 0;
        if (floatmode) return tf[t] != 0.0f;
        if (i64mode) return (ti[2 * t] != 0) || (ti[2 * t + 1] != 0);
        return ti[t] != 0;
    };

    int base = tid * 64;
    int cnt = 0;
    for (int k = 0; k < 64; k++) {
        int t = base + k;
        if (t == 0 || termAt(t)) cnt++;
    }
    cnts[tid] = cnt;
    __syncthreads();
    if (tid == 0) {
        int a = 0;
        for (int i = 0; i < 256; i++) { offs[i] = a; a += cnts[i]; }
        totS = a;
        meta->S = a;
    }
    __syncthreads();
    int S = totS;
    {
        int o = offs[tid];
        for (int k = 0; k < 64; k++) {
            int t = base + k;
            if (t == 0 || termAt(t)) seg_start[o++] = t;
        }
    }
    __syncthreads();
    for (int i = tid; i < S; i += 256)
        seg_len[i] = ((i + 1 < S) ? seg_start[i + 1] : T_LEN) - seg_start[i];
    __syncthreads();
    {
        int g = tid >> 4, r = tid & 15;
        int tot = 0;
        for (int i = g + 16 * r; i < S; i += 256) tot += seg_len[i];
        chain[tid] = tot;
    }
    __syncthreads();
    if (tid < NG) {
        int mx = 0;
        for (int r = 0; r < 16; r++) mx = max(mx, chain[tid * 16 + r]);
        meta->steps_g[tid] = mx;
    }
    int u = termAt(0);
    if (tid == 0) meta->use_h0 = !u;
    if (!u) {
        // h0 seed into group0/parity0/row0, coalesced layout Hb[kt][hh][m=0][j]
        for (int d2 = tid; d2 < DM; d2 += 256)
            Hbuf[(d2 >> 3) * 128 + (d2 & 7)] = (_Float16)h0[d2];
    }
}

// ---------------- XW = inputs @ Wx + b (fp16 MFMA, packed-col order, fp16 out) ----------------
__global__ __launch_bounds__(256) void xw_gemm_kernel(const half8* __restrict__ A, const half8* __restrict__ B,
                                                      const float* __restrict__ bias, _Float16* __restrict__ XW) {
    int bx = blockIdx.x, by = blockIdx.y;
    int w = threadIdx.x >> 6, l = threadIdx.x & 63;
    int mbase = bx * 64 + w * 16;
    int h = l >> 4, n = l & 15;
    floatx4 acc[8] = {};
    int arow = mbase + n;
#pragma unroll
    for (int kt = 0; kt < 16; kt++) {
        half8 a = A[(size_t)arow * 64 + kt * 4 + h];
#pragma unroll
        for (int nt = 0; nt < 8; nt++)
            acc[nt] = __builtin_amdgcn_mfma_f32_16x16x32_f16(a, B[((by * 8 + nt) * 16 + kt) * 64 + l], acc[nt], 0, 0, 0);
    }
#pragma unroll
    for (int nt = 0; nt < 8; nt++) {
        int tt = by * 8 + nt, q = tt & 3, cch = tt >> 2;
        float bv = bias[q * 512 + cch * 16 + n];
#pragma unroll
        for (int r = 0; r < 4; r++) {
            int row = mbase + h * 4 + r;
            XW[(size_t)row * NC + tt * 16 + n] = (_Float16)(acc[nt][r] + bv);
        }
    }
}

// ---------------- per-thread segment tracker ----------------
struct Trk { int seg, t0, s0, end, active; };

__device__ __forceinline__ void trk_init(Trk& k, int row, int g, int S,
                                         const int* __restrict__ ss, const int* __restrict__ sl) {
    int seg = g + 16 * row;
    k.seg = seg;
    if (seg < S) { k.t0 = ss[seg]; k.s0 = 0; k.end = sl[seg]; k.active = 1; }
    else { k.t0 = 0; k.s0 = 0; k.end = 0x7fffffff; k.active = 0; }
}

__device__ __forceinline__ int trk_step(Trk& k, int s, int S,
                                        const int* __restrict__ ss, const int* __restrict__ sl, int& t_out) {
    int z = !k.active;
    if (s > 0 && k.active && s == k.end) {
        int seg = k.seg + 256;
        if (seg < S) { k.seg = seg; k.t0 = ss[seg]; k.s0 = s; k.end = s + sl[seg]; z = 1; }
        else { k.active = 0; z = 1; }
    }
    t_out = k.active ? (k.t0 + (s - k.s0)) : 0;
    return z;
}

// ---------------- compute-wave step loop (R7 protocol), scope-templated ----------------
// L2C=true : group verified sc0-coherent (all on one XCD; probe tested WARM re-reads)
//            -> H/flag traffic via sc0 = XCD L2 coherence point (~3x lower RT).
// L2C=false: R7-proven agent(sc1)/MALL protocol, byte-identical.
template <bool L2C>
__device__ __forceinline__ void run_compute(
    const half8* __restrict__ PW, const _Float16* __restrict__ XW,
    const float* __restrict__ c0,
    const int* __restrict__ seg_start, const int* __restrict__ seg_len,
    u64* __restrict__ Hbuf, int* __restrict__ flags,
    int g, int jj, int w, int l, int steps, int S, int use_h0,
    u16 (&hstage)[2][NR][16], _Float16 (&xwstage)[2][NR][128],
    float (&outstage)[2][2][NR][32], int (&ioflag)[2], int (&outcnt)[2]) {
    const int c = jj * 2 + w;               // dim chunk 0..31 (16 dims each)
    const int n = l & 15, h = l >> 4;
    const int d = c * 16 + n;
    const int m = n;

    half8 bf[4][16];
#pragma unroll
    for (int q = 0; q < 4; q++)
#pragma unroll
        for (int kt = 0; kt < 16; kt++) {
            bf[q][kt] = PW[((c * 4 + q) * 16 + kt) * 64 + l];
            asm volatile("" : "+v"(bf[q][kt]));
        }

    Trk trkM; trk_init(trkM, n, g, S, seg_start, seg_len);
    Trk trk[4];
#pragma unroll
    for (int r = 0; r < 4; r++) trk_init(trk[r], h * 4 + r, g, S, seg_start, seg_len);

    float cc[4];
#pragma unroll
    for (int r = 0; r < 4; r++) {
        int row = h * 4 + r;
        cc[r] = (g == 0 && row == 0 && use_h0) ? c0[d] : 0.0f;
    }

    FragU zu; zu.q[0] = 0; zu.q[1] = 0;
    const half8 zfrag = zu.v;

    int* fl = flags + g * WVG;
    const int wfid = jj * 2 + w;
    const int pollidx = l & 31;

    // producer store coords (coalesced layout)
    const int b2 = l >> 5, m2 = (l >> 1) & 15, half = l & 1;
    const int ktc = c >> 1, hhp = (c & 1) * 2 + b2;
    const int ldsIdx = m2 * 4 + b2 * 2 + half;
    const size_t hwIdx = (size_t)(ktc * 4 + hhp) * 32 + m2 * 2 + half;

    for (int s = 0; s < steps; ++s) {
        // ---- trackers for step s ----
        int tdump;
        const int zM = trk_step(trkM, s, S, seg_start, seg_len, tdump);
        int zz[4];
#pragma unroll
        for (int r = 0; r < 4; r++)
            zz[r] = trk_step(trk[r], s, S, seg_start, seg_len, tdump);

        // ---- XW(s) from LDS stage (pre-staged by IO wave) ----
        while (__hip_atomic_load(&ioflag[s & 1], __ATOMIC_RELAXED, __HIP_MEMORY_SCOPE_WORKGROUP) < s)
            __builtin_amdgcn_s_sleep(1);
        asm volatile("" ::: "memory");
        float xwv[4][4];
#pragma unroll
        for (int q = 0; q < 4; q++)
#pragma unroll
            for (int r = 0; r < 4; r++)
                xwv[q][r] = (float)xwstage[s & 1][h * 4 + r][w * 64 + q * 16 + n];

        // ---- wait peers' step-(s-1) H publish ----
        if (s > 0) {
            if constexpr (L2C) {
                const int* flp = &fl[pollidx];
                while (true) {
                    int v;
                    asm volatile("global_load_dword %0, %1, off sc0" : "=v"(v) : "v"(flp) : "memory");
                    asm volatile("s_waitcnt vmcnt(0)" ::: "memory");
                    if (__all(v >= s)) break;
                    __builtin_amdgcn_s_sleep(1);
                }
                asm volatile("" ::: "memory");
            } else {
                while (true) {
                    int v = __hip_atomic_load(&fl[pollidx], __ATOMIC_RELAXED, __HIP_MEMORY_SCOPE_AGENT);
                    if (__all(v >= s)) break;
                    __builtin_amdgcn_s_sleep(1);
                }
                asm volatile("" ::: "memory");
            }
        }

        const int rp = s & 1;
        u64* Hr = Hbuf + (size_t)(g * 2 + rp) * (NR * DM / 4);
        u64* Hw = Hbuf + (size_t)(g * 2 + (rp ^ 1)) * (NR * DM / 4);

        // ---- A-fragment burst: 16 x dwordx4 ----
        u32x4 raw[16];
#pragma unroll
        for (int kt = 0; kt < 16; kt++) {
            const void* ap = (const char*)Hr + (((size_t)kt * 64 + h * 16 + m) << 4);
            if constexpr (L2C)
                asm volatile("global_load_dwordx4 %0, %1, off sc0" : "=v"(raw[kt]) : "v"(ap) : "memory");
            else
                asm volatile("global_load_dwordx4 %0, %1, off sc1" : "=v"(raw[kt]) : "v"(ap) : "memory");
        }
        asm volatile("s_waitcnt vmcnt(0)" ::: "memory");
        __builtin_amdgcn_sched_barrier(0);
        half8 afr[16];
#pragma unroll
        for (int kt = 0; kt < 16; kt++) {
            FragU u; u.r = raw[kt];
            afr[kt] = zM ? zfrag : u.v;
        }

        floatx4 acc[4] = {};
#pragma unroll
        for (int kt = 0; kt < 16; kt++) {
#pragma unroll
            for (int q = 0; q < 4; q++)
                acc[q] = __builtin_amdgcn_mfma_f32_16x16x32_f16(afr[kt], bf[q][kt], acc[q], 0, 0, 0);
        }

        float hnv[4], cnv[4];
#pragma unroll
        for (int r = 0; r < 4; r++) {
            float zi = acc[0][r] + xwv[0][r];
            float zf = acc[1][r] + xwv[1][r];
            float zg = acc[2][r] + xwv[2][r];
            float zo = acc[3][r] + xwv[3][r];
            float cprev = zz[r] ? 0.0f : cc[r];
            float cn = sigf(zf) * cprev + sigf(zi) * tanh_f(zg);
            float hn = sigf(zo) * tanh_f(cn);
            cc[r] = cn; hnv[r] = hn; cnv[r] = cn;
            hstage[w][h * 4 + r][n] = __builtin_bit_cast(u16, (_Float16)hn);
        }

        // wave-local regroup via LDS; order u16-writes -> u64-read (R3 lesson)
        asm volatile("s_waitcnt lgkmcnt(0)" ::: "memory");
        __builtin_amdgcn_sched_barrier(0);
        u64 pk = ((const u64*)&hstage[w][0][0])[ldsIdx];
        if constexpr (L2C) {
            u64* hwp = &Hw[hwIdx];
            asm volatile("global_store_dwordx2 %0, %1, off sc0" :: "v"(hwp), "v"(pk) : "memory");
        } else {
            __hip_atomic_store(&Hw[hwIdx], pk, __ATOMIC_RELAXED, __HIP_MEMORY_SCOPE_AGENT);
        }

        // drain this wave's H store (only op in queue), publish wave flag
        asm volatile("s_waitcnt vmcnt(0)" ::: "memory");
        if (l == 0) {
            int sp1 = s + 1;
            if constexpr (L2C) {
                int* flw = &fl[wfid];
                asm volatile("global_store_dword %0, %1, off sc0" :: "v"(flw), "v"(sp1) : "memory");
            } else {
                __hip_atomic_store(&fl[wfid], sp1, __ATOMIC_RELAXED, __HIP_MEMORY_SCOPE_AGENT);
            }
        }

        // ---- hand outputs to IO wave via LDS (lgkm traffic only) ----
        while (__hip_atomic_load(&outcnt[s & 1], __ATOMIC_RELAXED, __HIP_MEMORY_SCOPE_WORKGROUP) == 2)
            __builtin_amdgcn_s_sleep(1);
        asm volatile("" ::: "memory");
#pragma unroll
        for (int r = 0; r < 4; r++) {
            outstage[s & 1][0][h * 4 + r][w * 16 + n] = hnv[r];
            outstage[s & 1][1][h * 4 + r][w * 16 + n] = cnv[r];
        }
        asm volatile("s_waitcnt lgkmcnt(0)" ::: "memory");
        if (l == 0)
            __hip_atomic_fetch_add(&outcnt[s & 1], 1, __ATOMIC_RELAXED, __HIP_MEMORY_SCOPE_WORKGROUP);
    }
}

// ---------------- scan kernel: warm-reuse sc0 probe -> scoped step loop ----------------
__global__ __launch_bounds__(192, 1) void scan_kernel(
    const half8* __restrict__ PW, const _Float16* __restrict__ XW,
    const float* __restrict__ c0,
    const int* __restrict__ seg_start, const int* __restrict__ seg_len,
    const Meta* __restrict__ meta,
    u64* __restrict__ Hbuf, int* __restrict__ flags,
    u32* __restrict__ probebuf, int* __restrict__ verdict,
    float* __restrict__ out) {
    const int b = blockIdx.x;
    const int g = (b & 7) * 2 + (b >> 7);   // XCD-local groups IF dispatch is b%8 round-robin
    const int jj = (b >> 3) & 15;
    const int tid = threadIdx.x;
    const int w = tid >> 6, l = tid & 63;
    const int S = meta->S;
    const int steps = meta->steps_g[g];
    if (steps <= 0) return;
    const int use_h0 = meta->use_h0;

    __shared__ __align__(16) u16 hstage[2][NR][16];
    __shared__ __align__(16) _Float16 xwstage[2][NR][128];
    __shared__ __align__(16) float outstage[2][2][NR][32];
    __shared__ int ioflag[2];
    __shared__ int outcnt[2];
    __shared__ int sh_l2ok;

    if (tid == 0) { ioflag[0] = -1; ioflag[1] = -1; outcnt[0] = 0; outcnt[1] = 0; }

    // ---- sc0 coherence probe (wave 0 only; before ANY other L1 traffic) ----
    // Tests the R5 failure mode directly: rounds REUSE the same 16 slots, so a
    // passing round r>0 requires sc0 loads to see remote updates to addresses
    // already warm in this CU's caches. Bounded; early-bail; fallback is safe.
    if (w == 0) {
        int okflag = 1;
        u32* pb = probebuf + g * 64;   // 64 u32 (256B) per group
        for (int r = 0; r < PROBE_ROUNDS && okflag; ++r) {
            u32 tok = 0x10000u | ((u32)r << 8) | (u32)jj;
            if (l == 0) {
                u32* tp = pb + jj;
                asm volatile("global_store_dword %0, %1, off sc0" :: "v"(tp), "v"(tok) : "memory");
                asm volatile("s_waitcnt vmcnt(0)" ::: "memory");
            }
            u32 want = 0x10000u | ((u32)r << 8) | (u32)(l & 15);
            const u32* mp = pb + (l & 15);
            int got = 0;
            for (int it = 0; it < PROBE_CAP; ++it) {
                u32 tv;
                asm volatile("global_load_dword %0, %1, off sc0" : "=v"(tv) : "v"(mp) : "memory");
                asm volatile("s_waitcnt vmcnt(0)" ::: "memory");
                if (__all(tv >= want)) { got = 1; break; }   // monotone tokens: newer rounds pass
                __builtin_amdgcn_s_sleep(1);
            }
            if (!got) okflag = 0;
        }
        // verdict exchange: R4-proven agent protocol; every WG writes -> poll terminates
        if (l == 0)
            __hip_atomic_store(&verdict[g * 16 + jj], okflag ? 2 : 1, __ATOMIC_RELAXED, __HIP_MEMORY_SCOPE_AGENT);
        int vv;
        while (true) {
            vv = __hip_atomic_load(&verdict[g * 16 + (l & 15)], __ATOMIC_RELAXED, __HIP_MEMORY_SCOPE_AGENT);
            if (__all(vv != 0)) break;
            __builtin_amdgcn_s_sleep(1);
        }
        if (l == 0) sh_l2ok = __all(vv == 2) ? 1 : 0;   // group-uniform decision
    }
    __syncthreads();
    const int l2ok = sh_l2ok;

    float* outH = out;
    float* outC = out + (size_t)T_LEN * DM;
    float* outH2 = out + 2 * (size_t)T_LEN * DM;

    if (w < 2) {
        if (l2ok)
            run_compute<true>(PW, XW, c0, seg_start, seg_len, Hbuf, flags,
                              g, jj, w, l, steps, S, use_h0,
                              hstage, xwstage, outstage, ioflag, outcnt);
        else
            run_compute<false>(PW, XW, c0, seg_start, seg_len, Hbuf, flags,
                               g, jj, w, l, steps, S, use_h0,
                               hstage, xwstage, outstage, ioflag, outcnt);
    } else {
        // ================= IO WAVE (R7-verbatim) =================
        const int rX = l >> 4;
        const int rO = l >> 3;
        Trk trkX[4];
#pragma unroll
        for (int i = 0; i < 4; i++) trk_init(trkX[i], rX + 4 * i, g, S, seg_start, seg_len);
        Trk trkO[2];
        trk_init(trkO[0], rO, g, S, seg_start, seg_len);
        trk_init(trkO[1], rO + 8, g, S, seg_start, seg_len);

        auto stageXW = [&](int step, int buf) {
            int tX[4];
#pragma unroll
            for (int i = 0; i < 4; i++) (void)trk_step(trkX[i], step, S, seg_start, seg_len, tX[i]);
            u32x4 xr[4];
#pragma unroll
            for (int i = 0; i < 4; i++)
                xr[i] = *(const u32x4*)((const char*)XW + ((size_t)tX[i] * NC + jj * 128 + (l & 15) * 8) * 2);
#pragma unroll
            for (int i = 0; i < 4; i++)
                *(u32x4*)&xwstage[buf][rX + 4 * i][(l & 15) * 8] = xr[i];
            asm volatile("s_waitcnt lgkmcnt(0)" ::: "memory");
            if (l == 0)
                __hip_atomic_store(&ioflag[buf], step, __ATOMIC_RELAXED, __HIP_MEMORY_SCOPE_WORKGROUP);
        };

        stageXW(0, 0);
        stageXW(1, 1);

        for (int s = 0; s < steps; ++s) {
            int tO[2], aO[2];
#pragma unroll
            for (int j2 = 0; j2 < 2; j2++) {
                (void)trk_step(trkO[j2], s, S, seg_start, seg_len, tO[j2]);
                aO[j2] = trkO[j2].active;
            }
            while (__hip_atomic_load(&outcnt[s & 1], __ATOMIC_RELAXED, __HIP_MEMORY_SCOPE_WORKGROUP) < 2)
                __builtin_amdgcn_s_sleep(1);
            asm volatile("" ::: "memory");
            floatx4 hv[2], cv[2];
#pragma unroll
            for (int j2 = 0; j2 < 2; j2++) {
                hv[j2] = *(floatx4*)&outstage[s & 1][0][rO + 8 * j2][(l & 7) * 4];
                cv[j2] = *(floatx4*)&outstage[s & 1][1][rO + 8 * j2][(l & 7) * 4];
            }
            asm volatile("s_waitcnt lgkmcnt(0)" ::: "memory");
            __hip_atomic_store(&outcnt[s & 1], 0, __ATOMIC_RELAXED, __HIP_MEMORY_SCOPE_WORKGROUP);
#pragma unroll
            for (int j2 = 0; j2 < 2; j2++) {
                if (aO[j2]) {
                    size_t base = (size_t)tO[j2] * DM + jj * 32 + (l & 7) * 4;
                    *(floatx4*)&outH[base] = hv[j2];
                    *(floatx4*)&outC[base] = cv[j2];
                    *(floatx4*)&outH2[base] = hv[j2];
                }
            }
            stageXW(s + 2, s & 1);
        }
    }
}

extern "C" void kernel_launch(void* const* d_in, const int* in_sizes, int n_in,
                              void* d_out, int out_size, void* d_ws, size_t ws_size,
                              hipStream_t stream) {
    const float* inputs = (const float*)d_in[0];
    const void* terms = d_in[1];
    const float* c0 = (const float*)d_in[2];
    const float* h0 = (const float*)d_in[3];
    const float* Wx = (const float*)d_in[4];
    const float* Wh = (const float*)d_in[5];
    const float* bias = (const float*)d_in[6];
    float* out = (float*)d_out;

    size_t off = 0;
    auto take = [&](size_t bts) { size_t cur = off; off = (off + bts + 255) & ~(size_t)255; return cur; };
    size_t offXW = take((size_t)T_LEN * NC * 2);       // fp16 XW
    size_t offAin = take((size_t)T_LEN * DM * 2);
    size_t offPX = take((size_t)DM * NC * 2);
    size_t offPW = take((size_t)DM * NC * 2);
    size_t offSS = take((size_t)(T_LEN + 2) * 4);
    size_t offSL = take((size_t)(T_LEN + 2) * 4);
    size_t offH = take(2ull * NG * NR * DM * 2);
    size_t offFL = take((size_t)NG * WVG * 4);
    size_t offPB = take((size_t)NG * 256);             // sc0 probe slots
    size_t offVD = take((size_t)NG * WPG * 4);         // per-WG verdicts
    size_t offME = take(256);
    size_t total = off;
    (void)ws_size;

    char* W = (char*)d_ws;
    _Float16* Ain = (_Float16*)(W + offAin);
    half8* PX = (half8*)(W + offPX);
    half8* PWp = (half8*)(W + offPW);
    int* segS = (int*)(W + offSS);
    int* segL = (int*)(W + offSL);
    Meta* meta = (Meta*)(W + offME);
    _Float16* XWp = (_Float16*)(W + offXW);

    size_t zwords = (total - offH) / 4;  // Hbuf + flags + probe + verdict + meta contiguous
    zero_kernel<<<256, 256, 0, stream>>>((u32*)(W + offH), zwords);
    pack_f16_kernel<<<(T_LEN * DM / 8 + 255) / 256, 256, 0, stream>>>(inputs, Ain, T_LEN * DM / 8);
    pack_w_kernel<<<512, 256, 0, stream>>>(Wx, PX);
    pack_w_kernel<<<512, 256, 0, stream>>>(Wh, PWp);
    prep_kernel<<<1, 256, 0, stream>>>(terms, h0, segS, segL, meta, (_Float16*)(W + offH));

    dim3 gg(T_LEN / 64, NC / 128);
    xw_gemm_kernel<<<gg, 256, 0, stream>>>((const half8*)Ain, (const half8*)PX, bias, XWp);
    scan_kernel<<<256, 192, 0, stream>>>((const half8*)PWp, XWp, c0, segS, segL, meta,
                                         (u64*)(W + offH), (int*)(W + offFL),
                                         (u32*)(W + offPB), (int*)(W + offVD), out);
}

// Round 11
// 2069.295 us; speedup vs baseline: 1.8168x; 1.0705x over previous
//
#include <hip/hip_runtime.h>

typedef _Float16 half8 __attribute__((ext_vector_type(8)));
typedef float floatx4 __attribute__((ext_vector_type(4)));
typedef unsigned int u32x4 __attribute__((ext_vector_type(4)));
typedef unsigned long long u64;
typedef unsigned int u32;
typedef unsigned short u16;

#define T_LEN 16384
#define DM 512
#define NC 2048      // 4*DM
#define NG 16        // groups
#define NR 16        // segment rows (batch) per group
#define WPG 16       // workgroups per group
#define WVG 32       // compute waves per group (= flags per group)
#define PROBE_ROUNDS 6
#define PROBE_CAP 1200

struct Meta { int S; int use_h0; int steps_g[NG]; };

union FragU { u64 q[2]; u32x4 r; half8 v; };

__device__ __forceinline__ float sigf(float x) { return 1.0f / (1.0f + __expf(-x)); }
__device__ __forceinline__ float tanh_f(float x) { return 1.0f - 2.0f / (__expf(2.0f * x) + 1.0f); }

// ---------------- zero workspace region ----------------
__global__ void zero_kernel(u32* __restrict__ p, size_t nwords) {
    size_t i = (size_t)blockIdx.x * blockDim.x + threadIdx.x;
    size_t stride = (size_t)gridDim.x * blockDim.x;
    for (; i < nwords; i += stride) p[i] = 0u;
}

// ---------------- f32 -> f16 pack (row-major) ----------------
__global__ void pack_f16_kernel(const float* __restrict__ src, _Float16* __restrict__ dst, int n8) {
    int i = blockIdx.x * blockDim.x + threadIdx.x;
    if (i >= n8) return;
    const floatx4* s = (const floatx4*)src + (size_t)i * 2;
    floatx4 a = s[0], b = s[1];
    half8 o;
    o[0] = (_Float16)a[0]; o[1] = (_Float16)a[1]; o[2] = (_Float16)a[2]; o[3] = (_Float16)a[3];
    o[4] = (_Float16)b[0]; o[5] = (_Float16)b[1]; o[6] = (_Float16)b[2]; o[7] = (_Float16)b[3];
    ((half8*)dst)[i] = o;
}

// ---------------- weight pack to MFMA B-fragment order ----------------
__global__ __launch_bounds__(256) void pack_w_kernel(const float* __restrict__ src, half8* __restrict__ dst) {
    int wid = blockIdx.x * 4 + (threadIdx.x >> 6);  // 2048 = 128 tiles * 16 kt
    int l = threadIdx.x & 63;
    int tt = wid >> 4, kt = wid & 15;
    int q = tt & 3, cch = tt >> 2;
    int col = q * 512 + cch * 16 + (l & 15);
    int h = l >> 4;
    half8 o;
#pragma unroll
    for (int jj = 0; jj < 8; jj++) o[jj] = (_Float16)src[(size_t)(kt * 32 + h * 8 + jj) * NC + col];
    dst[(tt * 16 + kt) * 64 + l] = o;
}

// ---------------- prep: term dtype detect, segment extraction, chains ----------------
__global__ void prep_kernel(const void* __restrict__ termraw, const float* __restrict__ h0,
                            int* __restrict__ seg_start, int* __restrict__ seg_len,
                            Meta* __restrict__ meta, _Float16* __restrict__ Hbuf) {
    __shared__ int cnts[256], offs[256];
    __shared__ int nzm, oddnz, totS;
    __shared__ int chain[256];
    int tid = threadIdx.x;
    if (tid == 0) { nzm = 0; oddnz = 0; }
    __syncthreads();
    const unsigned char* tb = (const unsigned char*)termraw;
    const int* ti = (const int*)termraw;
    int lm = 0;
    for (int i = tid; i < T_LEN; i += 256) {
        if (tb[i]) {
            int p = i & 3;
            if (p == 1 || p == 2) lm |= 1;
            else if (p == 3) lm |= 2;
            else lm |= 4;
        }
    }
    if (lm) atomicOr(&nzm, lm);
    __syncthreads();
    int mm = nzm;
    int bytemode = (mm & 1) ? 1 : 0;
    int floatmode = (!bytemode && (mm & 2)) ? 1 : 0;
    int lo = 0;
    if (!bytemode && !floatmode) {
        for (int k2 = 2 * tid + 1; k2 < T_LEN; k2 += 512) if (ti[k2]) lo = 1;
    }
    if (lo) atomicOr(&oddnz, 1);
    __syncthreads();
    int i64mode = (!bytemode && !floatmode && oddnz == 0 && (mm & 4)) ? 1 : 0;
    const float* tf = (const float*)termraw;

    auto termAt = [&](int t) -> int {
        if (bytemode) return tb[t] != 0;
        if (floatmode) return tf[t] != 0.0f;
        if (i64mode) return (ti[2 * t] != 0) || (ti[2 * t + 1] != 0);
        return ti[t] != 0;
    };

    int base = tid * 64;
    int cnt = 0;
    for (int k = 0; k < 64; k++) {
        int t = base + k;
        if (t == 0 || termAt(t)) cnt++;
    }
    cnts[tid] = cnt;
    __syncthreads();
    if (tid == 0) {
        int a = 0;
        for (int i = 0; i < 256; i++) { offs[i] = a; a += cnts[i]; }
        totS = a;
        meta->S = a;
    }
    __syncthreads();
    int S = totS;
    {
        int o = offs[tid];
        for (int k = 0; k < 64; k++) {
            int t = base + k;
            if (t == 0 || termAt(t)) seg_start[o++] = t;
        }
    }
    __syncthreads();
    for (int i = tid; i < S; i += 256)
        seg_len[i] = ((i + 1 < S) ? seg_start[i + 1] : T_LEN) - seg_start[i];
    __syncthreads();
    {
        int g = tid >> 4, r = tid & 15;
        int tot = 0;
        for (int i = g + 16 * r; i < S; i += 256) tot += seg_len[i];
        chain[tid] = tot;
    }
    __syncthreads();
    if (tid < NG) {
        int mx = 0;
        for (int r = 0; r < 16; r++) mx = max(mx, chain[tid * 16 + r]);
        meta->steps_g[tid] = mx;
    }
    int u = termAt(0);
    if (tid == 0) meta->use_h0 = !u;
    if (!u) {
        // h0 seed into group0/parity0/row0, coalesced layout Hb[kt][hh][m=0][j]
        for (int d2 = tid; d2 < DM; d2 += 256)
            Hbuf[(d2 >> 3) * 128 + (d2 & 7)] = (_Float16)h0[d2];
    }
}

// ---------------- XW = inputs @ Wx + b (fp16 MFMA, packed-col order, fp16 out) ----------------
__global__ __launch_bounds__(256) void xw_gemm_kernel(const half8* __restrict__ A, const half8* __restrict__ B,
                                                      const float* __restrict__ bias, _Float16* __restrict__ XW) {
    int bx = blockIdx.x, by = blockIdx.y;
    int w = threadIdx.x >> 6, l = threadIdx.x & 63;
    int mbase = bx * 64 + w * 16;
    int h = l >> 4, n = l & 15;
    floatx4 acc[8] = {};
    int arow = mbase + n;
#pragma unroll
    for (int kt = 0; kt < 16; kt++) {
        half8 a = A[(size_t)arow * 64 + kt * 4 + h];
#pragma unroll
        for (int nt = 0; nt < 8; nt++)
            acc[nt] = __builtin_amdgcn_mfma_f32_16x16x32_f16(a, B[((by * 8 + nt) * 16 + kt) * 64 + l], acc[nt], 0, 0, 0);
    }
#pragma unroll
    for (int nt = 0; nt < 8; nt++) {
        int tt = by * 8 + nt, q = tt & 3, cch = tt >> 2;
        float bv = bias[q * 512 + cch * 16 + n];
#pragma unroll
        for (int r = 0; r < 4; r++) {
            int row = mbase + h * 4 + r;
            XW[(size_t)row * NC + tt * 16 + n] = (_Float16)(acc[nt][r] + bv);
        }
    }
}

// ---------------- per-thread segment tracker ----------------
struct Trk { int seg, t0, s0, end, active; };

__device__ __forceinline__ void trk_init(Trk& k, int row, int g, int S,
                                         const int* __restrict__ ss, const int* __restrict__ sl) {
    int seg = g + 16 * row;
    k.seg = seg;
    if (seg < S) { k.t0 = ss[seg]; k.s0 = 0; k.end = sl[seg]; k.active = 1; }
    else { k.t0 = 0; k.s0 = 0; k.end = 0x7fffffff; k.active = 0; }
}

__device__ __forceinline__ int trk_step(Trk& k, int s, int S,
                                        const int* __restrict__ ss, const int* __restrict__ sl, int& t_out) {
    int z = !k.active;
    if (s > 0 && k.active && s == k.end) {
        int seg = k.seg + 256;
        if (seg < S) { k.seg = seg; k.t0 = ss[seg]; k.s0 = s; k.end = s + sl[seg]; z = 1; }
        else { k.active = 0; z = 1; }
    }
    t_out = k.active ? (k.t0 + (s - k.s0)) : 0;
    return z;
}

// ---------------- compute-wave step loop (R7 protocol), scope-templated ----------------
// L2C=true : group is 16 WGs on ONE XCD (measured XCC_ID + warm-reuse probe passed)
//            -> H/flag traffic via sc0 = XCD L2 coherence point (~3x lower RT).
// L2C=false: R7-proven agent(sc1)/MALL protocol, byte-identical.
template <bool L2C>
__device__ __forceinline__ void run_compute(
    const half8* __restrict__ PW, const _Float16* __restrict__ XW,
    const float* __restrict__ c0,
    const int* __restrict__ seg_start, const int* __restrict__ seg_len,
    u64* __restrict__ Hbuf, int* __restrict__ flags,
    int g, int jj, int w, int l, int steps, int S, int use_h0,
    u16 (&hstage)[2][NR][16], _Float16 (&xwstage)[2][NR][128],
    float (&outstage)[2][2][NR][32], int (&ioflag)[2], int (&outcnt)[2]) {
    const int c = jj * 2 + w;               // dim chunk 0..31 (16 dims each)
    const int n = l & 15, h = l >> 4;
    const int d = c * 16 + n;
    const int m = n;

    half8 bf[4][16];
#pragma unroll
    for (int q = 0; q < 4; q++)
#pragma unroll
        for (int kt = 0; kt < 16; kt++) {
            bf[q][kt] = PW[((c * 4 + q) * 16 + kt) * 64 + l];
            asm volatile("" : "+v"(bf[q][kt]));
        }

    Trk trkM; trk_init(trkM, n, g, S, seg_start, seg_len);
    Trk trk[4];
#pragma unroll
    for (int r = 0; r < 4; r++) trk_init(trk[r], h * 4 + r, g, S, seg_start, seg_len);

    float cc[4];
#pragma unroll
    for (int r = 0; r < 4; r++) {
        int row = h * 4 + r;
        cc[r] = (g == 0 && row == 0 && use_h0) ? c0[d] : 0.0f;
    }

    FragU zu; zu.q[0] = 0; zu.q[1] = 0;
    const half8 zfrag = zu.v;

    int* fl = flags + g * WVG;
    const int wfid = jj * 2 + w;
    const int pollidx = l & 31;

    // producer store coords (coalesced layout)
    const int b2 = l >> 5, m2 = (l >> 1) & 15, half = l & 1;
    const int ktc = c >> 1, hhp = (c & 1) * 2 + b2;
    const int ldsIdx = m2 * 4 + b2 * 2 + half;
    const size_t hwIdx = (size_t)(ktc * 4 + hhp) * 32 + m2 * 2 + half;

    for (int s = 0; s < steps; ++s) {
        // ---- trackers for step s ----
        int tdump;
        const int zM = trk_step(trkM, s, S, seg_start, seg_len, tdump);
        int zz[4];
#pragma unroll
        for (int r = 0; r < 4; r++)
            zz[r] = trk_step(trk[r], s, S, seg_start, seg_len, tdump);

        // ---- XW(s) from LDS stage (pre-staged by IO wave) ----
        while (__hip_atomic_load(&ioflag[s & 1], __ATOMIC_RELAXED, __HIP_MEMORY_SCOPE_WORKGROUP) < s)
            __builtin_amdgcn_s_sleep(1);
        asm volatile("" ::: "memory");
        float xwv[4][4];
#pragma unroll
        for (int q = 0; q < 4; q++)
#pragma unroll
            for (int r = 0; r < 4; r++)
                xwv[q][r] = (float)xwstage[s & 1][h * 4 + r][w * 64 + q * 16 + n];

        // ---- wait peers' step-(s-1) H publish ----
        if (s > 0) {
            if constexpr (L2C) {
                const int* flp = &fl[pollidx];
                while (true) {
                    int v;
                    asm volatile("global_load_dword %0, %1, off sc0" : "=v"(v) : "v"(flp) : "memory");
                    asm volatile("s_waitcnt vmcnt(0)" ::: "memory");
                    if (__all(v >= s)) break;
                    __builtin_amdgcn_s_sleep(1);
                }
                asm volatile("" ::: "memory");
            } else {
                while (true) {
                    int v = __hip_atomic_load(&fl[pollidx], __ATOMIC_RELAXED, __HIP_MEMORY_SCOPE_AGENT);
                    if (__all(v >= s)) break;
                    __builtin_amdgcn_s_sleep(1);
                }
                asm volatile("" ::: "memory");
            }
        }

        const int rp = s & 1;
        u64* Hr = Hbuf + (size_t)(g * 2 + rp) * (NR * DM / 4);
        u64* Hw = Hbuf + (size_t)(g * 2 + (rp ^ 1)) * (NR * DM / 4);

        // ---- A-fragment burst: 16 x dwordx4 ----
        u32x4 raw[16];
#pragma unroll
        for (int kt = 0; kt < 16; kt++) {
            const void* ap = (const char*)Hr + (((size_t)kt * 64 + h * 16 + m) << 4);
            if constexpr (L2C)
                asm volatile("global_load_dwordx4 %0, %1, off sc0" : "=v"(raw[kt]) : "v"(ap) : "memory");
            else
                asm volatile("global_load_dwordx4 %0, %1, off sc1" : "=v"(raw[kt]) : "v"(ap) : "memory");
        }
        asm volatile("s_waitcnt vmcnt(0)" ::: "memory");
        __builtin_amdgcn_sched_barrier(0);
        half8 afr[16];
#pragma unroll
        for (int kt = 0; kt < 16; kt++) {
            FragU u; u.r = raw[kt];
            afr[kt] = zM ? zfrag : u.v;
        }

        floatx4 acc[4] = {};
#pragma unroll
        for (int kt = 0; kt < 16; kt++) {
#pragma unroll
            for (int q = 0; q < 4; q++)
                acc[q] = __builtin_amdgcn_mfma_f32_16x16x32_f16(afr[kt], bf[q][kt], acc[q], 0, 0, 0);
        }

        float hnv[4], cnv[4];
#pragma unroll
        for (int r = 0; r < 4; r++) {
            float zi = acc[0][r] + xwv[0][r];
            float zf = acc[1][r] + xwv[1][r];
            float zg = acc[2][r] + xwv[2][r];
            float zo = acc[3][r] + xwv[3][r];
            float cprev = zz[r] ? 0.0f : cc[r];
            float cn = sigf(zf) * cprev + sigf(zi) * tanh_f(zg);
            float hn = sigf(zo) * tanh_f(cn);
            cc[r] = cn; hnv[r] = hn; cnv[r] = cn;
            hstage[w][h * 4 + r][n] = __builtin_bit_cast(u16, (_Float16)hn);
        }

        // wave-local regroup via LDS; order u16-writes -> u64-read (R3 lesson)
        asm volatile("s_waitcnt lgkmcnt(0)" ::: "memory");
        __builtin_amdgcn_sched_barrier(0);
        u64 pk = ((const u64*)&hstage[w][0][0])[ldsIdx];
        if constexpr (L2C) {
            u64* hwp = &Hw[hwIdx];
            asm volatile("global_store_dwordx2 %0, %1, off sc0" :: "v"(hwp), "v"(pk) : "memory");
        } else {
            __hip_atomic_store(&Hw[hwIdx], pk, __ATOMIC_RELAXED, __HIP_MEMORY_SCOPE_AGENT);
        }

        // drain this wave's H store (only op in queue), publish wave flag
        asm volatile("s_waitcnt vmcnt(0)" ::: "memory");
        if (l == 0) {
            int sp1 = s + 1;
            if constexpr (L2C) {
                int* flw = &fl[wfid];
                asm volatile("global_store_dword %0, %1, off sc0" :: "v"(flw), "v"(sp1) : "memory");
            } else {
                __hip_atomic_store(&fl[wfid], sp1, __ATOMIC_RELAXED, __HIP_MEMORY_SCOPE_AGENT);
            }
        }

        // ---- hand outputs to IO wave via LDS (lgkm traffic only) ----
        while (__hip_atomic_load(&outcnt[s & 1], __ATOMIC_RELAXED, __HIP_MEMORY_SCOPE_WORKGROUP) == 2)
            __builtin_amdgcn_s_sleep(1);
        asm volatile("" ::: "memory");
#pragma unroll
        for (int r = 0; r < 4; r++) {
            outstage[s & 1][0][h * 4 + r][w * 16 + n] = hnv[r];
            outstage[s & 1][1][h * 4 + r][w * 16 + n] = cnv[r];
        }
        asm volatile("s_waitcnt lgkmcnt(0)" ::: "memory");
        if (l == 0)
            __hip_atomic_fetch_add(&outcnt[s & 1], 1, __ATOMIC_RELAXED, __HIP_MEMORY_SCOPE_WORKGROUP);
    }
}

// ---------------- scan kernel: XCC_ID regrouping -> probe -> scoped step loop ----------------
__global__ __launch_bounds__(192, 1) void scan_kernel(
    const half8* __restrict__ PW, const _Float16* __restrict__ XW,
    const float* __restrict__ c0,
    const int* __restrict__ seg_start, const int* __restrict__ seg_len,
    const Meta* __restrict__ meta,
    u64* __restrict__ Hbuf, int* __restrict__ flags,
    u32* __restrict__ probebuf, int* __restrict__ verdict,
    int* __restrict__ xcdbuf, int* __restrict__ asg,
    float* __restrict__ out) {
    const int b = blockIdx.x;
    const int tid = threadIdx.x;
    const int w = tid >> 6, l = tid & 63;
    const int S = meta->S;
    const int use_h0 = meta->use_h0;

    __shared__ __align__(16) u16 hstage[2][NR][16];
    __shared__ __align__(16) _Float16 xwstage[2][NR][128];
    __shared__ __align__(16) float outstage[2][2][NR][32];
    __shared__ int ioflag[2];
    __shared__ int outcnt[2];
    __shared__ int sh_asg;
    __shared__ int sh_l2ok;

    if (tid == 0) { ioflag[0] = -1; ioflag[1] = -1; outcnt[0] = 0; outcnt[1] = 0; }

    // ---- phase 1: publish measured XCC_ID; WG 0 builds XCD-local groups ----
    if (tid == 0) {
        u32 xcc = __builtin_amdgcn_s_getreg(63508) & 7;  // HW_REG_XCC_ID (m09-verified)
        __hip_atomic_store(&xcdbuf[b], (int)(xcc + 1), __ATOMIC_RELAXED, __HIP_MEMORY_SCOPE_AGENT);
    }
    if (b == 0 && tid == 0) {
        // pass 1: counts per XCD (two-pass to avoid a 256-int scratch array)
        int cxc[8] = {0, 0, 0, 0, 0, 0, 0, 0};
        for (int w2 = 0; w2 < 256; ++w2) {
            int v;
            while ((v = __hip_atomic_load(&xcdbuf[w2], __ATOMIC_RELAXED, __HIP_MEMORY_SCOPE_AGENT)) == 0)
                __builtin_amdgcn_s_sleep(1);
            cxc[(v - 1) & 7]++;
        }
        int base_g[8], ng_x[8], gi = 0;
        for (int x = 0; x < 8; ++x) {
            int t = cxc[x] >> 4;
            if (t > NG - gi) t = NG - gi;
            ng_x[x] = t; base_g[x] = gi; gi += t;
        }
        const int lg = gi;   // leftover (mixed) groups start here
        int kx[8] = {0, 0, 0, 0, 0, 0, 0, 0};
        int lk = 0;
        for (int w2 = 0; w2 < 256; ++w2) {
            int x = (__hip_atomic_load(&xcdbuf[w2], __ATOMIC_RELAXED, __HIP_MEMORY_SCOPE_AGENT) - 1) & 7;
            int g2, j2, l2;
            if (kx[x] < ng_x[x] * 16) {
                g2 = base_g[x] + (kx[x] >> 4); j2 = kx[x] & 15; l2 = 1; kx[x]++;
            } else {
                g2 = lg + (lk >> 4); j2 = lk & 15; l2 = 0; lk++;
            }
            __hip_atomic_store(&asg[w2], ((l2 << 8) | (g2 << 4) | j2) + 1,
                               __ATOMIC_RELAXED, __HIP_MEMORY_SCOPE_AGENT);
        }
    }
    if (tid == 0) {
        int v;
        while ((v = __hip_atomic_load(&asg[b], __ATOMIC_RELAXED, __HIP_MEMORY_SCOPE_AGENT)) == 0)
            __builtin_amdgcn_s_sleep(1);
        sh_asg = v - 1;
    }
    __syncthreads();
    const int g = (sh_asg >> 4) & 15;
    const int jj = sh_asg & 15;
    const int l2cand = (sh_asg >> 8) & 1;

    // ---- phase 2: warm-reuse sc0 probe (wave 0; candidates only) + group verdict ----
    if (w == 0) {
        int okflag = l2cand;
        if (l2cand) {
            u32* pb = probebuf + g * 64;
            for (int r = 0; r < PROBE_ROUNDS && okflag; ++r) {
                u32 tok = 0x10000u | ((u32)r << 8) | (u32)jj;
                if (l == 0) {
                    u32* tp = pb + jj;
                    asm volatile("global_store_dword %0, %1, off sc0" :: "v"(tp), "v"(tok) : "memory");
                    asm volatile("s_waitcnt vmcnt(0)" ::: "memory");
                }
                u32 want = 0x10000u | ((u32)r << 8) | (u32)(l & 15);
                const u32* mp = pb + (l & 15);
                int got = 0;
                for (int it = 0; it < PROBE_CAP; ++it) {
                    u32 tv;
                    asm volatile("global_load_dword %0, %1, off sc0" : "=v"(tv) : "v"(mp) : "memory");
                    asm volatile("s_waitcnt vmcnt(0)" ::: "memory");
                    if (__all(tv >= want)) { got = 1; break; }
                    __builtin_amdgcn_s_sleep(1);
                }
                if (!got) okflag = 0;
            }
        }
        if (l == 0)
            __hip_atomic_store(&verdict[g * 16 + jj], okflag ? 2 : 1, __ATOMIC_RELAXED, __HIP_MEMORY_SCOPE_AGENT);
        int vv;
        while (true) {
            vv = __hip_atomic_load(&verdict[g * 16 + (l & 15)], __ATOMIC_RELAXED, __HIP_MEMORY_SCOPE_AGENT);
            if (__all(vv != 0)) break;
            __builtin_amdgcn_s_sleep(1);
        }
        if (l == 0) sh_l2ok = __all(vv == 2) ? 1 : 0;
    }
    __syncthreads();
    const int l2ok = sh_l2ok;

    const int steps = meta->steps_g[g];
    if (steps <= 0) return;

    float* outH = out;
    float* outC = out + (size_t)T_LEN * DM;
    float* outH2 = out + 2 * (size_t)T_LEN * DM;

    if (w < 2) {
        if (l2ok)
            run_compute<true>(PW, XW, c0, seg_start, seg_len, Hbuf, flags,
                              g, jj, w, l, steps, S, use_h0,
                              hstage, xwstage, outstage, ioflag, outcnt);
        else
            run_compute<false>(PW, XW, c0, seg_start, seg_len, Hbuf, flags,
                               g, jj, w, l, steps, S, use_h0,
                               hstage, xwstage, outstage, ioflag, outcnt);
    } else {
        // ================= IO WAVE (R7-verbatim) =================
        const int rX = l >> 4;
        const int rO = l >> 3;
        Trk trkX[4];
#pragma unroll
        for (int i = 0; i < 4; i++) trk_init(trkX[i], rX + 4 * i, g, S, seg_start, seg_len);
        Trk trkO[2];
        trk_init(trkO[0], rO, g, S, seg_start, seg_len);
        trk_init(trkO[1], rO + 8, g, S, seg_start, seg_len);

        auto stageXW = [&](int step, int buf) {
            int tX[4];
#pragma unroll
            for (int i = 0; i < 4; i++) (void)trk_step(trkX[i], step, S, seg_start, seg_len, tX[i]);
            u32x4 xr[4];
#pragma unroll
            for (int i = 0; i < 4; i++)
                xr[i] = *(const u32x4*)((const char*)XW + ((size_t)tX[i] * NC + jj * 128 + (l & 15) * 8) * 2);
#pragma unroll
            for (int i = 0; i < 4; i++)
                *(u32x4*)&xwstage[buf][rX + 4 * i][(l & 15) * 8] = xr[i];
            asm volatile("s_waitcnt lgkmcnt(0)" ::: "memory");
            if (l == 0)
                __hip_atomic_store(&ioflag[buf], step, __ATOMIC_RELAXED, __HIP_MEMORY_SCOPE_WORKGROUP);
        };

        stageXW(0, 0);
        stageXW(1, 1);

        for (int s = 0; s < steps; ++s) {
            int tO[2], aO[2];
#pragma unroll
            for (int j2 = 0; j2 < 2; j2++) {
                (void)trk_step(trkO[j2], s, S, seg_start, seg_len, tO[j2]);
                aO[j2] = trkO[j2].active;
            }
            while (__hip_atomic_load(&outcnt[s & 1], __ATOMIC_RELAXED, __HIP_MEMORY_SCOPE_WORKGROUP) < 2)
                __builtin_amdgcn_s_sleep(1);
            asm volatile("" ::: "memory");
            floatx4 hv[2], cv[2];
#pragma unroll
            for (int j2 = 0; j2 < 2; j2++) {
                hv[j2] = *(floatx4*)&outstage[s & 1][0][rO + 8 * j2][(l & 7) * 4];
                cv[j2] = *(floatx4*)&outstage[s & 1][1][rO + 8 * j2][(l & 7) * 4];
            }
            asm volatile("s_waitcnt lgkmcnt(0)" ::: "memory");
            __hip_atomic_store(&outcnt[s & 1], 0, __ATOMIC_RELAXED, __HIP_MEMORY_SCOPE_WORKGROUP);
#pragma unroll
            for (int j2 = 0; j2 < 2; j2++) {
                if (aO[j2]) {
                    size_t base = (size_t)tO[j2] * DM + jj * 32 + (l & 7) * 4;
                    *(floatx4*)&outH[base] = hv[j2];
                    *(floatx4*)&outC[base] = cv[j2];
                    *(floatx4*)&outH2[base] = hv[j2];
                }
            }
            stageXW(s + 2, s & 1);
        }
    }
}

extern "C" void kernel_launch(void* const* d_in, const int* in_sizes, int n_in,
                              void* d_out, int out_size, void* d_ws, size_t ws_size,
                              hipStream_t stream) {
    const float* inputs = (const float*)d_in[0];
    const void* terms = d_in[1];
    const float* c0 = (const float*)d_in[2];
    const float* h0 = (const float*)d_in[3];
    const float* Wx = (const float*)d_in[4];
    const float* Wh = (const float*)d_in[5];
    const float* bias = (const float*)d_in[6];
    float* out = (float*)d_out;

    size_t off = 0;
    auto take = [&](size_t bts) { size_t cur = off; off = (off + bts + 255) & ~(size_t)255; return cur; };
    size_t offXW = take((size_t)T_LEN * NC * 2);       // fp16 XW
    size_t offAin = take((size_t)T_LEN * DM * 2);
    size_t offPX = take((size_t)DM * NC * 2);
    size_t offPW = take((size_t)DM * NC * 2);
    size_t offSS = take((size_t)(T_LEN + 2) * 4);
    size_t offSL = take((size_t)(T_LEN + 2) * 4);
    size_t offH = take(2ull * NG * NR * DM * 2);
    size_t offFL = take((size_t)NG * WVG * 4);
    size_t offPB = take((size_t)NG * 256);             // sc0 probe slots
    size_t offVD = take((size_t)NG * WPG * 4);         // per-WG verdicts
    size_t offXC = take(256 * 4);                      // measured XCC_ID per WG
    size_t offAS = take(256 * 4);                      // leader-assigned (g,jj,l2)
    size_t offME = take(256);
    size_t total = off;
    (void)ws_size;

    char* W = (char*)d_ws;
    _Float16* Ain = (_Float16*)(W + offAin);
    half8* PX = (half8*)(W + offPX);
    half8* PWp = (half8*)(W + offPW);
    int* segS = (int*)(W + offSS);
    int* segL = (int*)(W + offSL);
    Meta* meta = (Meta*)(W + offME);
    _Float16* XWp = (_Float16*)(W + offXW);

    size_t zwords = (total - offH) / 4;  // Hbuf + flags + probe + verdict + xcd + asg + meta
    zero_kernel<<<256, 256, 0, stream>>>((u32*)(W + offH), zwords);
    pack_f16_kernel<<<(T_LEN * DM / 8 + 255) / 256, 256, 0, stream>>>(inputs, Ain, T_LEN * DM / 8);
    pack_w_kernel<<<512, 256, 0, stream>>>(Wx, PX);
    pack_w_kernel<<<512, 256, 0, stream>>>(Wh, PWp);
    prep_kernel<<<1, 256, 0, stream>>>(terms, h0, segS, segL, meta, (_Float16*)(W + offH));

    dim3 gg(T_LEN / 64, NC / 128);
    xw_gemm_kernel<<<gg, 256, 0, stream>>>((const half8*)Ain, (const half8*)PX, bias, XWp);
    scan_kernel<<<256, 192, 0, stream>>>((const half8*)PWp, XWp, c0, segS, segL, meta,
                                         (u64*)(W + offH), (int*)(W + offFL),
                                         (u32*)(W + offPB), (int*)(W + offVD),
                                         (int*)(W + offXC), (int*)(W + offAS), out);
}

// Round 12
// 1838.965 us; speedup vs baseline: 2.0444x; 1.1252x over previous
//
#include <hip/hip_runtime.h>

typedef _Float16 half8 __attribute__((ext_vector_type(8)));
typedef float floatx4 __attribute__((ext_vector_type(4)));
typedef unsigned int u32x4 __attribute__((ext_vector_type(4)));
typedef unsigned long long u64;
typedef unsigned int u32;
typedef unsigned short u16;

#define T_LEN 16384
#define DM 512
#define NC 2048      // 4*DM
#define NG 16        // groups
#define NR 16        // segment rows (batch) per group
#define WPG 16       // workgroups per group
#define WVG 32       // compute waves per group (= flags per group)

struct Meta { int S; int use_h0; int steps_g[NG]; };

union FragU { u64 q[2]; u32x4 r; half8 v; };

__device__ __forceinline__ float sigf(float x) { return 1.0f / (1.0f + __expf(-x)); }
__device__ __forceinline__ float tanh_f(float x) { return 1.0f - 2.0f / (__expf(2.0f * x) + 1.0f); }

// ---------------- zero workspace region ----------------
__global__ void zero_kernel(u32* __restrict__ p, size_t nwords) {
    size_t i = (size_t)blockIdx.x * blockDim.x + threadIdx.x;
    size_t stride = (size_t)gridDim.x * blockDim.x;
    for (; i < nwords; i += stride) p[i] = 0u;
}

// ---------------- f32 -> f16 pack (row-major) ----------------
__global__ void pack_f16_kernel(const float* __restrict__ src, _Float16* __restrict__ dst, int n8) {
    int i = blockIdx.x * blockDim.x + threadIdx.x;
    if (i >= n8) return;
    const floatx4* s = (const floatx4*)src + (size_t)i * 2;
    floatx4 a = s[0], b = s[1];
    half8 o;
    o[0] = (_Float16)a[0]; o[1] = (_Float16)a[1]; o[2] = (_Float16)a[2]; o[3] = (_Float16)a[3];
    o[4] = (_Float16)b[0]; o[5] = (_Float16)b[1]; o[6] = (_Float16)b[2]; o[7] = (_Float16)b[3];
    ((half8*)dst)[i] = o;
}

// ---------------- weight pack to MFMA B-fragment order ----------------
__global__ __launch_bounds__(256) void pack_w_kernel(const float* __restrict__ src, half8* __restrict__ dst) {
    int wid = blockIdx.x * 4 + (threadIdx.x >> 6);  // 2048 = 128 tiles * 16 kt
    int l = threadIdx.x & 63;
    int tt = wid >> 4, kt = wid & 15;
    int q = tt & 3, cch = tt >> 2;
    int col = q * 512 + cch * 16 + (l & 15);
    int h = l >> 4;
    half8 o;
#pragma unroll
    for (int jj = 0; jj < 8; jj++) o[jj] = (_Float16)src[(size_t)(kt * 32 + h * 8 + jj) * NC + col];
    dst[(tt * 16 + kt) * 64 + l] = o;
}

// ---------------- prep: term dtype detect, segment extraction, chains ----------------
__global__ void prep_kernel(const void* __restrict__ termraw, const float* __restrict__ h0,
                            int* __restrict__ seg_start, int* __restrict__ seg_len,
                            Meta* __restrict__ meta, _Float16* __restrict__ Hbuf) {
    __shared__ int cnts[256], offs[256];
    __shared__ int nzm, oddnz, totS;
    __shared__ int chain[256];
    int tid = threadIdx.x;
    if (tid == 0) { nzm = 0; oddnz = 0; }
    __syncthreads();
    const unsigned char* tb = (const unsigned char*)termraw;
    const int* ti = (const int*)termraw;
    int lm = 0;
    for (int i = tid; i < T_LEN; i += 256) {
        if (tb[i]) {
            int p = i & 3;
            if (p == 1 || p == 2) lm |= 1;
            else if (p == 3) lm |= 2;
            else lm |= 4;
        }
    }
    if (lm) atomicOr(&nzm, lm);
    __syncthreads();
    int mm = nzm;
    int bytemode = (mm & 1) ? 1 : 0;
    int floatmode = (!bytemode && (mm & 2)) ? 1 : 0;
    int lo = 0;
    if (!bytemode && !floatmode) {
        for (int k2 = 2 * tid + 1; k2 < T_LEN; k2 += 512) if (ti[k2]) lo = 1;
    }
    if (lo) atomicOr(&oddnz, 1);
    __syncthreads();
    int i64mode = (!bytemode && !floatmode && oddnz == 0 && (mm & 4)) ? 1 : 0;
    const float* tf = (const float*)termraw;

    auto termAt = [&](int t) -> int {
        if (bytemode) return tb[t] != 0;
        if (floatmode) return tf[t] != 0.0f;
        if (i64mode) return (ti[2 * t] != 0) || (ti[2 * t + 1] != 0);
        return ti[t] != 0;
    };

    int base = tid * 64;
    int cnt = 0;
    for (int k = 0; k < 64; k++) {
        int t = base + k;
        if (t == 0 || termAt(t)) cnt++;
    }
    cnts[tid] = cnt;
    __syncthreads();
    if (tid == 0) {
        int a = 0;
        for (int i = 0; i < 256; i++) { offs[i] = a; a += cnts[i]; }
        totS = a;
        meta->S = a;
    }
    __syncthreads();
    int S = totS;
    {
        int o = offs[tid];
        for (int k = 0; k < 64; k++) {
            int t = base + k;
            if (t == 0 || termAt(t)) seg_start[o++] = t;
        }
    }
    __syncthreads();
    for (int i = tid; i < S; i += 256)
        seg_len[i] = ((i + 1 < S) ? seg_start[i + 1] : T_LEN) - seg_start[i];
    __syncthreads();
    {
        int g = tid >> 4, r = tid & 15;
        int tot = 0;
        for (int i = g + 16 * r; i < S; i += 256) tot += seg_len[i];
        chain[tid] = tot;
    }
    __syncthreads();
    if (tid < NG) {
        int mx = 0;
        for (int r = 0; r < 16; r++) mx = max(mx, chain[tid * 16 + r]);
        meta->steps_g[tid] = mx;
    }
    int u = termAt(0);
    if (tid == 0) meta->use_h0 = !u;
    if (!u) {
        // h0 seed into group0/parity0/row0, coalesced layout Hb[kt][hh][m=0][j]
        for (int d2 = tid; d2 < DM; d2 += 256)
            Hbuf[(d2 >> 3) * 128 + (d2 & 7)] = (_Float16)h0[d2];
    }
}

// ---------------- XW = inputs @ Wx + b (fp16 MFMA, packed-col order, fp16 out) ----------------
__global__ __launch_bounds__(256) void xw_gemm_kernel(const half8* __restrict__ A, const half8* __restrict__ B,
                                                      const float* __restrict__ bias, _Float16* __restrict__ XW) {
    int bx = blockIdx.x, by = blockIdx.y;
    int w = threadIdx.x >> 6, l = threadIdx.x & 63;
    int mbase = bx * 64 + w * 16;
    int h = l >> 4, n = l & 15;
    floatx4 acc[8] = {};
    int arow = mbase + n;
#pragma unroll
    for (int kt = 0; kt < 16; kt++) {
        half8 a = A[(size_t)arow * 64 + kt * 4 + h];
#pragma unroll
        for (int nt = 0; nt < 8; nt++)
            acc[nt] = __builtin_amdgcn_mfma_f32_16x16x32_f16(a, B[((by * 8 + nt) * 16 + kt) * 64 + l], acc[nt], 0, 0, 0);
    }
#pragma unroll
    for (int nt = 0; nt < 8; nt++) {
        int tt = by * 8 + nt, q = tt & 3, cch = tt >> 2;
        float bv = bias[q * 512 + cch * 16 + n];
#pragma unroll
        for (int r = 0; r < 4; r++) {
            int row = mbase + h * 4 + r;
            XW[(size_t)row * NC + tt * 16 + n] = (_Float16)(acc[nt][r] + bv);
        }
    }
}

// ---------------- per-thread segment tracker ----------------
struct Trk { int seg, t0, s0, end, active; };

__device__ __forceinline__ void trk_init(Trk& k, int row, int g, int S,
                                         const int* __restrict__ ss, const int* __restrict__ sl) {
    int seg = g + 16 * row;
    k.seg = seg;
    if (seg < S) { k.t0 = ss[seg]; k.s0 = 0; k.end = sl[seg]; k.active = 1; }
    else { k.t0 = 0; k.s0 = 0; k.end = 0x7fffffff; k.active = 0; }
}

__device__ __forceinline__ int trk_step(Trk& k, int s, int S,
                                        const int* __restrict__ ss, const int* __restrict__ sl, int& t_out) {
    int z = !k.active;
    if (s > 0 && k.active && s == k.end) {
        int seg = k.seg + 256;
        if (seg < S) { k.seg = seg; k.t0 = ss[seg]; k.s0 = s; k.end = s + sl[seg]; z = 1; }
        else { k.active = 0; z = 1; }
    }
    t_out = k.active ? (k.t0 + (s - k.s0)) : 0;
    return z;
}

// ---------------- recurrent scan v12: R7 protocol + 4-deep pipelined flag poll ----------------
// Detect latency was ~1.5 poll-RTs (single in-flight sample). Now 4 poll loads are
// in flight; in-order vmcnt retirement (m135) validates them one by one at
// vmcnt(3/2/1/0), quartering the sampling period. Values are tied through the
// waitcnt asm ("+v") so the compiler cannot hoist the checks (rule #18).
__global__ __launch_bounds__(192, 1) void scan_kernel(
    const half8* __restrict__ PW, const _Float16* __restrict__ XW,
    const float* __restrict__ c0,
    const int* __restrict__ seg_start, const int* __restrict__ seg_len,
    const Meta* __restrict__ meta,
    u64* __restrict__ Hbuf, int* __restrict__ flags,
    float* __restrict__ out) {
    const int b = blockIdx.x;
    const int g = (b & 7) * 2 + (b >> 7);
    const int jj = (b >> 3) & 15;
    const int tid = threadIdx.x;
    const int w = tid >> 6, l = tid & 63;
    const int S = meta->S;
    const int steps = meta->steps_g[g];
    if (steps <= 0) return;
    const int use_h0 = meta->use_h0;

    __shared__ __align__(16) u16 hstage[2][NR][16];
    __shared__ __align__(16) _Float16 xwstage[2][NR][128];
    __shared__ __align__(16) float outstage[2][2][NR][32];
    __shared__ int ioflag[2];
    __shared__ int outcnt[2];

    if (tid == 0) { ioflag[0] = -1; ioflag[1] = -1; outcnt[0] = 0; outcnt[1] = 0; }
    __syncthreads();

    float* outH = out;
    float* outC = out + (size_t)T_LEN * DM;
    float* outH2 = out + 2 * (size_t)T_LEN * DM;

    if (w < 2) {
        // ================= COMPUTE WAVE =================
        const int c = jj * 2 + w;
        const int n = l & 15, h = l >> 4;
        const int d = c * 16 + n;
        const int m = n;

        half8 bf[4][16];
#pragma unroll
        for (int q = 0; q < 4; q++)
#pragma unroll
            for (int kt = 0; kt < 16; kt++) {
                bf[q][kt] = PW[((c * 4 + q) * 16 + kt) * 64 + l];
                asm volatile("" : "+v"(bf[q][kt]));
            }

        Trk trkM; trk_init(trkM, n, g, S, seg_start, seg_len);
        Trk trk[4];
#pragma unroll
        for (int r = 0; r < 4; r++) trk_init(trk[r], h * 4 + r, g, S, seg_start, seg_len);

        float cc[4];
#pragma unroll
        for (int r = 0; r < 4; r++) {
            int row = h * 4 + r;
            cc[r] = (g == 0 && row == 0 && use_h0) ? c0[d] : 0.0f;
        }

        FragU zu; zu.q[0] = 0; zu.q[1] = 0;
        const half8 zfrag = zu.v;

        int* fl = flags + g * WVG;
        const int wfid = jj * 2 + w;
        const int pollidx = l & 31;

        const int b2 = l >> 5, m2 = (l >> 1) & 15, half = l & 1;
        const int ktc = c >> 1, hhp = (c & 1) * 2 + b2;
        const int ldsIdx = m2 * 4 + b2 * 2 + half;
        const size_t hwIdx = (size_t)(ktc * 4 + hhp) * 32 + m2 * 2 + half;

        for (int s = 0; s < steps; ++s) {
            // ---- trackers for step s ----
            int tdump;
            const int zM = trk_step(trkM, s, S, seg_start, seg_len, tdump);
            int zz[4];
#pragma unroll
            for (int r = 0; r < 4; r++)
                zz[r] = trk_step(trk[r], s, S, seg_start, seg_len, tdump);

            // ---- XW(s) from LDS stage (pre-staged by IO wave) ----
            while (__hip_atomic_load(&ioflag[s & 1], __ATOMIC_RELAXED, __HIP_MEMORY_SCOPE_WORKGROUP) < s)
                __builtin_amdgcn_s_sleep(1);
            asm volatile("" ::: "memory");
            float xwv[4][4];
#pragma unroll
            for (int q = 0; q < 4; q++)
#pragma unroll
                for (int r = 0; r < 4; r++)
                    xwv[q][r] = (float)xwstage[s & 1][h * 4 + r][w * 64 + q * 16 + n];

            // ---- pipelined 4-deep flag poll (sampling period ~RT/4) ----
            if (s > 0) {
                const int* flp = &fl[pollidx];
                int v0, v1, v2, v3;
                while (true) {
                    asm volatile(
                        "global_load_dword %0, %4, off sc1\n\t"
                        "global_load_dword %1, %4, off sc1\n\t"
                        "global_load_dword %2, %4, off sc1\n\t"
                        "global_load_dword %3, %4, off sc1"
                        : "=&v"(v0), "=&v"(v1), "=&v"(v2), "=&v"(v3)
                        : "v"(flp) : "memory");
                    asm volatile("s_waitcnt vmcnt(3)" : "+v"(v0) :: "memory");
                    if (__all(v0 >= s)) { asm volatile("s_waitcnt vmcnt(0)" ::: "memory"); break; }
                    asm volatile("s_waitcnt vmcnt(2)" : "+v"(v1) :: "memory");
                    if (__all(v1 >= s)) { asm volatile("s_waitcnt vmcnt(0)" ::: "memory"); break; }
                    asm volatile("s_waitcnt vmcnt(1)" : "+v"(v2) :: "memory");
                    if (__all(v2 >= s)) { asm volatile("s_waitcnt vmcnt(0)" ::: "memory"); break; }
                    asm volatile("s_waitcnt vmcnt(0)" : "+v"(v3) :: "memory");
                    if (__all(v3 >= s)) break;
                }
                asm volatile("" ::: "memory");
            }

            const int rp = s & 1;
            u64* Hr = Hbuf + (size_t)(g * 2 + rp) * (NR * DM / 4);
            u64* Hw = Hbuf + (size_t)(g * 2 + (rp ^ 1)) * (NR * DM / 4);

            // ---- A-fragment burst: 16 x dwordx4 sc1 ----
            u32x4 raw[16];
#pragma unroll
            for (int kt = 0; kt < 16; kt++) {
                const void* ap = (const char*)Hr + (((size_t)kt * 64 + h * 16 + m) << 4);
                asm volatile("global_load_dwordx4 %0, %1, off sc1" : "=v"(raw[kt]) : "v"(ap) : "memory");
            }
            asm volatile("s_waitcnt vmcnt(0)" ::: "memory");
            __builtin_amdgcn_sched_barrier(0);
            half8 afr[16];
#pragma unroll
            for (int kt = 0; kt < 16; kt++) {
                FragU u; u.r = raw[kt];
                afr[kt] = zM ? zfrag : u.v;
            }

            floatx4 acc[4] = {};
#pragma unroll
            for (int kt = 0; kt < 16; kt++) {
#pragma unroll
                for (int q = 0; q < 4; q++)
                    acc[q] = __builtin_amdgcn_mfma_f32_16x16x32_f16(afr[kt], bf[q][kt], acc[q], 0, 0, 0);
            }

            float hnv[4], cnv[4];
#pragma unroll
            for (int r = 0; r < 4; r++) {
                float zi = acc[0][r] + xwv[0][r];
                float zf = acc[1][r] + xwv[1][r];
                float zg = acc[2][r] + xwv[2][r];
                float zo = acc[3][r] + xwv[3][r];
                float cprev = zz[r] ? 0.0f : cc[r];
                float cn = sigf(zf) * cprev + sigf(zi) * tanh_f(zg);
                float hn = sigf(zo) * tanh_f(cn);
                cc[r] = cn; hnv[r] = hn; cnv[r] = cn;
                hstage[w][h * 4 + r][n] = __builtin_bit_cast(u16, (_Float16)hn);
            }

            // wave-local regroup via LDS; order u16-writes -> u64-read (R3 lesson)
            asm volatile("s_waitcnt lgkmcnt(0)" ::: "memory");
            __builtin_amdgcn_sched_barrier(0);
            u64 pk = ((const u64*)&hstage[w][0][0])[ldsIdx];
            __hip_atomic_store(&Hw[hwIdx], pk, __ATOMIC_RELAXED, __HIP_MEMORY_SCOPE_AGENT);

            // drain this wave's H store (only op in queue), publish wave flag
            asm volatile("s_waitcnt vmcnt(0)" ::: "memory");
            if (l == 0)
                __hip_atomic_store(&fl[wfid], s + 1, __ATOMIC_RELAXED, __HIP_MEMORY_SCOPE_AGENT);

            // ---- hand outputs to IO wave via LDS (lgkm traffic only) ----
            while (__hip_atomic_load(&outcnt[s & 1], __ATOMIC_RELAXED, __HIP_MEMORY_SCOPE_WORKGROUP) == 2)
                __builtin_amdgcn_s_sleep(1);
            asm volatile("" ::: "memory");
#pragma unroll
            for (int r = 0; r < 4; r++) {
                outstage[s & 1][0][h * 4 + r][w * 16 + n] = hnv[r];
                outstage[s & 1][1][h * 4 + r][w * 16 + n] = cnv[r];
            }
            asm volatile("s_waitcnt lgkmcnt(0)" ::: "memory");
            if (l == 0)
                __hip_atomic_fetch_add(&outcnt[s & 1], 1, __ATOMIC_RELAXED, __HIP_MEMORY_SCOPE_WORKGROUP);
        }
    } else {
        // ================= IO WAVE =================
        const int rX = l >> 4;
        const int rO = l >> 3;
        Trk trkX[4];
#pragma unroll
        for (int i = 0; i < 4; i++) trk_init(trkX[i], rX + 4 * i, g, S, seg_start, seg_len);
        Trk trkO[2];
        trk_init(trkO[0], rO, g, S, seg_start, seg_len);
        trk_init(trkO[1], rO + 8, g, S, seg_start, seg_len);

        auto stageXW = [&](int step, int buf) {
            int tX[4];
#pragma unroll
            for (int i = 0; i < 4; i++) (void)trk_step(trkX[i], step, S, seg_start, seg_len, tX[i]);
            u32x4 xr[4];
#pragma unroll
            for (int i = 0; i < 4; i++)
                xr[i] = *(const u32x4*)((const char*)XW + ((size_t)tX[i] * NC + jj * 128 + (l & 15) * 8) * 2);
#pragma unroll
            for (int i = 0; i < 4; i++)
                *(u32x4*)&xwstage[buf][rX + 4 * i][(l & 15) * 8] = xr[i];
            asm volatile("s_waitcnt lgkmcnt(0)" ::: "memory");
            if (l == 0)
                __hip_atomic_store(&ioflag[buf], step, __ATOMIC_RELAXED, __HIP_MEMORY_SCOPE_WORKGROUP);
        };

        stageXW(0, 0);
        stageXW(1, 1);

        for (int s = 0; s < steps; ++s) {
            int tO[2], aO[2];
#pragma unroll
            for (int j2 = 0; j2 < 2; j2++) {
                (void)trk_step(trkO[j2], s, S, seg_start, seg_len, tO[j2]);
                aO[j2] = trkO[j2].active;
            }
            while (__hip_atomic_load(&outcnt[s & 1], __ATOMIC_RELAXED, __HIP_MEMORY_SCOPE_WORKGROUP) < 2)
                __builtin_amdgcn_s_sleep(1);
            asm volatile("" ::: "memory");
            floatx4 hv[2], cv[2];
#pragma unroll
            for (int j2 = 0; j2 < 2; j2++) {
                hv[j2] = *(floatx4*)&outstage[s & 1][0][rO + 8 * j2][(l & 7) * 4];
                cv[j2] = *(floatx4*)&outstage[s & 1][1][rO + 8 * j2][(l & 7) * 4];
            }
            asm volatile("s_waitcnt lgkmcnt(0)" ::: "memory");
            __hip_atomic_store(&outcnt[s & 1], 0, __ATOMIC_RELAXED, __HIP_MEMORY_SCOPE_WORKGROUP);
#pragma unroll
            for (int j2 = 0; j2 < 2; j2++) {
                if (aO[j2]) {
                    size_t base = (size_t)tO[j2] * DM + jj * 32 + (l & 7) * 4;
                    *(floatx4*)&outH[base] = hv[j2];
                    *(floatx4*)&outC[base] = cv[j2];
                    *(floatx4*)&outH2[base] = hv[j2];
                }
            }
            stageXW(s + 2, s & 1);
        }
    }
}

extern "C" void kernel_launch(void* const* d_in, const int* in_sizes, int n_in,
                              void* d_out, int out_size, void* d_ws, size_t ws_size,
                              hipStream_t stream) {
    const float* inputs = (const float*)d_in[0];
    const void* terms = d_in[1];
    const float* c0 = (const float*)d_in[2];
    const float* h0 = (const float*)d_in[3];
    const float* Wx = (const float*)d_in[4];
    const float* Wh = (const float*)d_in[5];
    const float* bias = (const float*)d_in[6];
    float* out = (float*)d_out;

    size_t off = 0;
    auto take = [&](size_t bts) { size_t cur = off; off = (off + bts + 255) & ~(size_t)255; return cur; };
    size_t offXW = take((size_t)T_LEN * NC * 2);       // fp16 XW
    size_t offAin = take((size_t)T_LEN * DM * 2);
    size_t offPX = take((size_t)DM * NC * 2);
    size_t offPW = take((size_t)DM * NC * 2);
    size_t offSS = take((size_t)(T_LEN + 2) * 4);
    size_t offSL = take((size_t)(T_LEN + 2) * 4);
    size_t offH = take(2ull * NG * NR * DM * 2);
    size_t offFL = take((size_t)NG * WVG * 4);
    size_t offME = take(256);
    size_t total = off;
    (void)ws_size;

    char* W = (char*)d_ws;
    _Float16* Ain = (_Float16*)(W + offAin);
    half8* PX = (half8*)(W + offPX);
    half8* PWp = (half8*)(W + offPW);
    int* segS = (int*)(W + offSS);
    int* segL = (int*)(W + offSL);
    Meta* meta = (Meta*)(W + offME);
    _Float16* XWp = (_Float16*)(W + offXW);

    size_t zwords = (total - offH) / 4;  // Hbuf + flags + meta contiguous
    zero_kernel<<<256, 256, 0, stream>>>((u32*)(W + offH), zwords);
    pack_f16_kernel<<<(T_LEN * DM / 8 + 255) / 256, 256, 0, stream>>>(inputs, Ain, T_LEN * DM / 8);
    pack_w_kernel<<<512, 256, 0, stream>>>(Wx, PX);
    pack_w_kernel<<<512, 256, 0, stream>>>(Wh, PWp);
    prep_kernel<<<1, 256, 0, stream>>>(terms, h0, segS, segL, meta, (_Float16*)(W + offH));

    dim3 gg(T_LEN / 64, NC / 128);
    xw_gemm_kernel<<<gg, 256, 0, stream>>>((const half8*)Ain, (const half8*)PX, bias, XWp);
    scan_kernel<<<256, 192, 0, stream>>>((const half8*)PWp, XWp, c0, segS, segL, meta,
                                         (u64*)(W + offH), (int*)(W + offFL), out);
}

// Round 13
// 1808.378 us; speedup vs baseline: 2.0789x; 1.0169x over previous
//
#include <hip/hip_runtime.h>

typedef _Float16 half8 __attribute__((ext_vector_type(8)));
typedef float floatx4 __attribute__((ext_vector_type(4)));
typedef unsigned int u32x4 __attribute__((ext_vector_type(4)));
typedef unsigned long long u64;
typedef unsigned int u32;
typedef unsigned short u16;

#define T_LEN 16384
#define DM 512
#define NC 2048      // 4*DM
#define NG 16        // groups
#define NR 16        // segment rows (batch) per group
#define WPG 16       // workgroups per group
#define WVG 32       // compute waves per group (= flags per group)

struct Meta { int S; int use_h0; int steps_g[NG]; };

union FragU { u64 q[2]; u32x4 r; half8 v; };

__device__ __forceinline__ float sigf(float x) { return 1.0f / (1.0f + __expf(-x)); }
__device__ __forceinline__ float tanh_f(float x) { return 1.0f - 2.0f / (__expf(2.0f * x) + 1.0f); }

// ---------------- zero workspace region ----------------
__global__ void zero_kernel(u32* __restrict__ p, size_t nwords) {
    size_t i = (size_t)blockIdx.x * blockDim.x + threadIdx.x;
    size_t stride = (size_t)gridDim.x * blockDim.x;
    for (; i < nwords; i += stride) p[i] = 0u;
}

// ---------------- f32 -> f16 pack (row-major) ----------------
__global__ void pack_f16_kernel(const float* __restrict__ src, _Float16* __restrict__ dst, int n8) {
    int i = blockIdx.x * blockDim.x + threadIdx.x;
    if (i >= n8) return;
    const floatx4* s = (const floatx4*)src + (size_t)i * 2;
    floatx4 a = s[0], b = s[1];
    half8 o;
    o[0] = (_Float16)a[0]; o[1] = (_Float16)a[1]; o[2] = (_Float16)a[2]; o[3] = (_Float16)a[3];
    o[4] = (_Float16)b[0]; o[5] = (_Float16)b[1]; o[6] = (_Float16)b[2]; o[7] = (_Float16)b[3];
    ((half8*)dst)[i] = o;
}

// ---------------- weight pack to MFMA B-fragment order ----------------
__global__ __launch_bounds__(256) void pack_w_kernel(const float* __restrict__ src, half8* __restrict__ dst) {
    int wid = blockIdx.x * 4 + (threadIdx.x >> 6);  // 2048 = 128 tiles * 16 kt
    int l = threadIdx.x & 63;
    int tt = wid >> 4, kt = wid & 15;
    int q = tt & 3, cch = tt >> 2;
    int col = q * 512 + cch * 16 + (l & 15);
    int h = l >> 4;
    half8 o;
#pragma unroll
    for (int jj = 0; jj < 8; jj++) o[jj] = (_Float16)src[(size_t)(kt * 32 + h * 8 + jj) * NC + col];
    dst[(tt * 16 + kt) * 64 + l] = o;
}

// ---------------- prep: term dtype detect, segment extraction, chains ----------------
__global__ void prep_kernel(const void* __restrict__ termraw, const float* __restrict__ h0,
                            int* __restrict__ seg_start, int* __restrict__ seg_len,
                            Meta* __restrict__ meta, _Float16* __restrict__ Hbuf) {
    __shared__ int cnts[256], offs[256];
    __shared__ int nzm, oddnz, totS;
    __shared__ int chain[256];
    int tid = threadIdx.x;
    if (tid == 0) { nzm = 0; oddnz = 0; }
    __syncthreads();
    const unsigned char* tb = (const unsigned char*)termraw;
    const int* ti = (const int*)termraw;
    int lm = 0;
    for (int i = tid; i < T_LEN; i += 256) {
        if (tb[i]) {
            int p = i & 3;
            if (p == 1 || p == 2) lm |= 1;
            else if (p == 3) lm |= 2;
            else lm |= 4;
        }
    }
    if (lm) atomicOr(&nzm, lm);
    __syncthreads();
    int mm = nzm;
    int bytemode = (mm & 1) ? 1 : 0;
    int floatmode = (!bytemode && (mm & 2)) ? 1 : 0;
    int lo = 0;
    if (!bytemode && !floatmode) {
        for (int k2 = 2 * tid + 1; k2 < T_LEN; k2 += 512) if (ti[k2]) lo = 1;
    }
    if (lo) atomicOr(&oddnz, 1);
    __syncthreads();
    int i64mode = (!bytemode && !floatmode && oddnz == 0 && (mm & 4)) ? 1 : 0;
    const float* tf = (const float*)termraw;

    auto termAt = [&](int t) -> int {
        if (bytemode) return tb[t] != 0;
        if (floatmode) return tf[t] != 0.0f;
        if (i64mode) return (ti[2 * t] != 0) || (ti[2 * t + 1] != 0);
        return ti[t] != 0;
    };

    int base = tid * 64;
    int cnt = 0;
    for (int k = 0; k < 64; k++) {
        int t = base + k;
        if (t == 0 || termAt(t)) cnt++;
    }
    cnts[tid] = cnt;
    __syncthreads();
    if (tid == 0) {
        int a = 0;
        for (int i = 0; i < 256; i++) { offs[i] = a; a += cnts[i]; }
        totS = a;
        meta->S = a;
    }
    __syncthreads();
    int S = totS;
    {
        int o = offs[tid];
        for (int k = 0; k < 64; k++) {
            int t = base + k;
            if (t == 0 || termAt(t)) seg_start[o++] = t;
        }
    }
    __syncthreads();
    for (int i = tid; i < S; i += 256)
        seg_len[i] = ((i + 1 < S) ? seg_start[i + 1] : T_LEN) - seg_start[i];
    __syncthreads();
    {
        int g = tid >> 4, r = tid & 15;
        int tot = 0;
        for (int i = g + 16 * r; i < S; i += 256) tot += seg_len[i];
        chain[tid] = tot;
    }
    __syncthreads();
    if (tid < NG) {
        int mx = 0;
        for (int r = 0; r < 16; r++) mx = max(mx, chain[tid * 16 + r]);
        meta->steps_g[tid] = mx;
    }
    int u = termAt(0);
    if (tid == 0) meta->use_h0 = !u;
    if (!u) {
        // h0 seed into group0/parity0/row0, coalesced layout Hb[kt][hh][m=0][j]
        for (int d2 = tid; d2 < DM; d2 += 256)
            Hbuf[(d2 >> 3) * 128 + (d2 & 7)] = (_Float16)h0[d2];
    }
}

// ---------------- XW = inputs @ Wx + b (fp16 MFMA, packed-col order, fp16 out) ----------------
__global__ __launch_bounds__(256) void xw_gemm_kernel(const half8* __restrict__ A, const half8* __restrict__ B,
                                                      const float* __restrict__ bias, _Float16* __restrict__ XW) {
    int bx = blockIdx.x, by = blockIdx.y;
    int w = threadIdx.x >> 6, l = threadIdx.x & 63;
    int mbase = bx * 64 + w * 16;
    int h = l >> 4, n = l & 15;
    floatx4 acc[8] = {};
    int arow = mbase + n;
#pragma unroll
    for (int kt = 0; kt < 16; kt++) {
        half8 a = A[(size_t)arow * 64 + kt * 4 + h];
#pragma unroll
        for (int nt = 0; nt < 8; nt++)
            acc[nt] = __builtin_amdgcn_mfma_f32_16x16x32_f16(a, B[((by * 8 + nt) * 16 + kt) * 64 + l], acc[nt], 0, 0, 0);
    }
#pragma unroll
    for (int nt = 0; nt < 8; nt++) {
        int tt = by * 8 + nt, q = tt & 3, cch = tt >> 2;
        float bv = bias[q * 512 + cch * 16 + n];
#pragma unroll
        for (int r = 0; r < 4; r++) {
            int row = mbase + h * 4 + r;
            XW[(size_t)row * NC + tt * 16 + n] = (_Float16)(acc[nt][r] + bv);
        }
    }
}

// ---------------- per-thread segment tracker ----------------
struct Trk { int seg, t0, s0, end, active; };

__device__ __forceinline__ void trk_init(Trk& k, int row, int g, int S,
                                         const int* __restrict__ ss, const int* __restrict__ sl) {
    int seg = g + 16 * row;
    k.seg = seg;
    if (seg < S) { k.t0 = ss[seg]; k.s0 = 0; k.end = sl[seg]; k.active = 1; }
    else { k.t0 = 0; k.s0 = 0; k.end = 0x7fffffff; k.active = 0; }
}

__device__ __forceinline__ int trk_step(Trk& k, int s, int S,
                                        const int* __restrict__ ss, const int* __restrict__ sl, int& t_out) {
    int z = !k.active;
    if (s > 0 && k.active && s == k.end) {
        int seg = k.seg + 256;
        if (seg < S) { k.seg = seg; k.t0 = ss[seg]; k.s0 = s; k.end = s + sl[seg]; z = 1; }
        else { k.active = 0; z = 1; }
    }
    t_out = k.active ? (k.t0 + (s - k.s0)) : 0;
    return z;
}

// ---------------- recurrent scan v7 (best verified): wave-specialized IO ----------------
// 3 waves/WG: waves 0,1 compute (MALL-only VMEM queue: sc1 A-burst, sc1 H-store,
// drain, flag, single-sample poll), wave 2 = IO (XW prefetch into LDS + out drains).
__global__ __launch_bounds__(192, 1) void scan_kernel(
    const half8* __restrict__ PW, const _Float16* __restrict__ XW,
    const float* __restrict__ c0,
    const int* __restrict__ seg_start, const int* __restrict__ seg_len,
    const Meta* __restrict__ meta,
    u64* __restrict__ Hbuf, int* __restrict__ flags,
    float* __restrict__ out) {
    const int b = blockIdx.x;
    const int g = (b & 7) * 2 + (b >> 7);   // XCD-local groups (perf hint only)
    const int jj = (b >> 3) & 15;
    const int tid = threadIdx.x;
    const int w = tid >> 6, l = tid & 63;
    const int S = meta->S;
    const int steps = meta->steps_g[g];
    if (steps <= 0) return;
    const int use_h0 = meta->use_h0;

    __shared__ __align__(16) u16 hstage[2][NR][16];
    __shared__ __align__(16) _Float16 xwstage[2][NR][128];   // [buf][row][WG's 128 packed cols]
    __shared__ __align__(16) float outstage[2][2][NR][32];   // [buf][h|c][row][WG's 32 dims]
    __shared__ int ioflag[2];   // step id staged in xwstage[b] (-1 = none)
    __shared__ int outcnt[2];   // 0=free, 1=one wave done, 2=ready for IO

    if (tid == 0) { ioflag[0] = -1; ioflag[1] = -1; outcnt[0] = 0; outcnt[1] = 0; }
    __syncthreads();

    float* outH = out;
    float* outC = out + (size_t)T_LEN * DM;
    float* outH2 = out + 2 * (size_t)T_LEN * DM;

    if (w < 2) {
        // ================= COMPUTE WAVE =================
        const int c = jj * 2 + w;               // dim chunk 0..31 (16 dims each)
        const int n = l & 15, h = l >> 4;
        const int d = c * 16 + n;
        const int m = n;

        half8 bf[4][16];
#pragma unroll
        for (int q = 0; q < 4; q++)
#pragma unroll
            for (int kt = 0; kt < 16; kt++) {
                bf[q][kt] = PW[((c * 4 + q) * 16 + kt) * 64 + l];
                asm volatile("" : "+v"(bf[q][kt]));
            }

        Trk trkM; trk_init(trkM, n, g, S, seg_start, seg_len);
        Trk trk[4];
#pragma unroll
        for (int r = 0; r < 4; r++) trk_init(trk[r], h * 4 + r, g, S, seg_start, seg_len);

        float cc[4];
#pragma unroll
        for (int r = 0; r < 4; r++) {
            int row = h * 4 + r;
            cc[r] = (g == 0 && row == 0 && use_h0) ? c0[d] : 0.0f;
        }

        FragU zu; zu.q[0] = 0; zu.q[1] = 0;
        const half8 zfrag = zu.v;

        int* fl = flags + g * WVG;
        const int wfid = jj * 2 + w;
        const int pollidx = l & 31;

        // producer store coords (coalesced layout)
        const int b2 = l >> 5, m2 = (l >> 1) & 15, half = l & 1;
        const int ktc = c >> 1, hhp = (c & 1) * 2 + b2;
        const int ldsIdx = m2 * 4 + b2 * 2 + half;
        const size_t hwIdx = (size_t)(ktc * 4 + hhp) * 32 + m2 * 2 + half;

        for (int s = 0; s < steps; ++s) {
            // ---- trackers for step s (registers; rare L2 loads on transitions) ----
            int tdump;
            const int zM = trk_step(trkM, s, S, seg_start, seg_len, tdump);
            int zz[4];
#pragma unroll
            for (int r = 0; r < 4; r++)
                zz[r] = trk_step(trk[r], s, S, seg_start, seg_len, tdump);

            // ---- XW(s) from LDS stage (lgkm only; pre-staged by IO wave) ----
            while (__hip_atomic_load(&ioflag[s & 1], __ATOMIC_RELAXED, __HIP_MEMORY_SCOPE_WORKGROUP) < s)
                __builtin_amdgcn_s_sleep(1);
            asm volatile("" ::: "memory");
            float xwv[4][4];
#pragma unroll
            for (int q = 0; q < 4; q++)
#pragma unroll
                for (int r = 0; r < 4; r++)
                    xwv[q][r] = (float)xwstage[s & 1][h * 4 + r][w * 64 + q * 16 + n];

            // ---- wait peers' step-(s-1) H publish (clean MALL-only queue) ----
            if (s > 0) {
                while (true) {
                    int v = __hip_atomic_load(&fl[pollidx], __ATOMIC_RELAXED, __HIP_MEMORY_SCOPE_AGENT);
                    if (__all(v >= s)) break;
                    __builtin_amdgcn_s_sleep(1);
                }
                asm volatile("" ::: "memory");
            }

            const int rp = s & 1;
            u64* Hr = Hbuf + (size_t)(g * 2 + rp) * (NR * DM / 4);
            u64* Hw = Hbuf + (size_t)(g * 2 + (rp ^ 1)) * (NR * DM / 4);

            // ---- A-fragment burst: 16 x dwordx4 sc1 ----
            u32x4 raw[16];
#pragma unroll
            for (int kt = 0; kt < 16; kt++) {
                const void* ap = (const char*)Hr + (((size_t)kt * 64 + h * 16 + m) << 4);
                asm volatile("global_load_dwordx4 %0, %1, off sc1" : "=v"(raw[kt]) : "v"(ap) : "memory");
            }
            asm volatile("s_waitcnt vmcnt(0)" ::: "memory");
            __builtin_amdgcn_sched_barrier(0);
            half8 afr[16];
#pragma unroll
            for (int kt = 0; kt < 16; kt++) {
                FragU u; u.r = raw[kt];
                afr[kt] = zM ? zfrag : u.v;
            }

            floatx4 acc[4] = {};
#pragma unroll
            for (int kt = 0; kt < 16; kt++) {
#pragma unroll
                for (int q = 0; q < 4; q++)
                    acc[q] = __builtin_amdgcn_mfma_f32_16x16x32_f16(afr[kt], bf[q][kt], acc[q], 0, 0, 0);
            }

            float hnv[4], cnv[4];
#pragma unroll
            for (int r = 0; r < 4; r++) {
                float zi = acc[0][r] + xwv[0][r];
                float zf = acc[1][r] + xwv[1][r];
                float zg = acc[2][r] + xwv[2][r];
                float zo = acc[3][r] + xwv[3][r];
                float cprev = zz[r] ? 0.0f : cc[r];
                float cn = sigf(zf) * cprev + sigf(zi) * tanh_f(zg);
                float hn = sigf(zo) * tanh_f(cn);
                cc[r] = cn; hnv[r] = hn; cnv[r] = cn;
                hstage[w][h * 4 + r][n] = __builtin_bit_cast(u16, (_Float16)hn);
            }

            // wave-local regroup via LDS; order u16-writes -> u64-read (R3 lesson)
            asm volatile("s_waitcnt lgkmcnt(0)" ::: "memory");
            __builtin_amdgcn_sched_barrier(0);
            u64 pk = ((const u64*)&hstage[w][0][0])[ldsIdx];
            __hip_atomic_store(&Hw[hwIdx], pk, __ATOMIC_RELAXED, __HIP_MEMORY_SCOPE_AGENT);

            // drain this wave's H store (only op in queue), publish wave flag
            asm volatile("s_waitcnt vmcnt(0)" ::: "memory");
            if (l == 0)
                __hip_atomic_store(&fl[wfid], s + 1, __ATOMIC_RELAXED, __HIP_MEMORY_SCOPE_AGENT);

            // ---- hand outputs to IO wave via LDS (lgkm traffic only) ----
            while (__hip_atomic_load(&outcnt[s & 1], __ATOMIC_RELAXED, __HIP_MEMORY_SCOPE_WORKGROUP) == 2)
                __builtin_amdgcn_s_sleep(1);
            asm volatile("" ::: "memory");
#pragma unroll
            for (int r = 0; r < 4; r++) {
                outstage[s & 1][0][h * 4 + r][w * 16 + n] = hnv[r];
                outstage[s & 1][1][h * 4 + r][w * 16 + n] = cnv[r];
            }
            asm volatile("s_waitcnt lgkmcnt(0)" ::: "memory");
            if (l == 0)
                __hip_atomic_fetch_add(&outcnt[s & 1], 1, __ATOMIC_RELAXED, __HIP_MEMORY_SCOPE_WORKGROUP);
        }
    } else {
        // ================= IO WAVE =================
        const int rX = l >> 4;        // staging rows rX+4i, lane part (l&15)
        const int rO = l >> 3;        // out rows rO, rO+8, lane part (l&7)
        Trk trkX[4];
#pragma unroll
        for (int i = 0; i < 4; i++) trk_init(trkX[i], rX + 4 * i, g, S, seg_start, seg_len);
        Trk trkO[2];
        trk_init(trkO[0], rO, g, S, seg_start, seg_len);
        trk_init(trkO[1], rO + 8, g, S, seg_start, seg_len);

        auto stageXW = [&](int step, int buf) {
            int tX[4];
#pragma unroll
            for (int i = 0; i < 4; i++) (void)trk_step(trkX[i], step, S, seg_start, seg_len, tX[i]);
            u32x4 xr[4];
#pragma unroll
            for (int i = 0; i < 4; i++)
                xr[i] = *(const u32x4*)((const char*)XW + ((size_t)tX[i] * NC + jj * 128 + (l & 15) * 8) * 2);
#pragma unroll
            for (int i = 0; i < 4; i++)
                *(u32x4*)&xwstage[buf][rX + 4 * i][(l & 15) * 8] = xr[i];
            asm volatile("s_waitcnt lgkmcnt(0)" ::: "memory");
            if (l == 0)
                __hip_atomic_store(&ioflag[buf], step, __ATOMIC_RELAXED, __HIP_MEMORY_SCOPE_WORKGROUP);
        };

        // prologue: stage XW(0), XW(1)
        stageXW(0, 0);
        stageXW(1, 1);

        for (int s = 0; s < steps; ++s) {
            int tO[2], aO[2];
#pragma unroll
            for (int j2 = 0; j2 < 2; j2++) {
                (void)trk_step(trkO[j2], s, S, seg_start, seg_len, tO[j2]);
                aO[j2] = trkO[j2].active;
            }
            // wait both compute waves' outstage for step s
            while (__hip_atomic_load(&outcnt[s & 1], __ATOMIC_RELAXED, __HIP_MEMORY_SCOPE_WORKGROUP) < 2)
                __builtin_amdgcn_s_sleep(1);
            asm volatile("" ::: "memory");
            floatx4 hv[2], cv[2];
#pragma unroll
            for (int j2 = 0; j2 < 2; j2++) {
                hv[j2] = *(floatx4*)&outstage[s & 1][0][rO + 8 * j2][(l & 7) * 4];
                cv[j2] = *(floatx4*)&outstage[s & 1][1][rO + 8 * j2][(l & 7) * 4];
            }
            asm volatile("s_waitcnt lgkmcnt(0)" ::: "memory");
            __hip_atomic_store(&outcnt[s & 1], 0, __ATOMIC_RELAXED, __HIP_MEMORY_SCOPE_WORKGROUP);
#pragma unroll
            for (int j2 = 0; j2 < 2; j2++) {
                if (aO[j2]) {
                    size_t base = (size_t)tO[j2] * DM + jj * 32 + (l & 7) * 4;
                    *(floatx4*)&outH[base] = hv[j2];
                    *(floatx4*)&outC[base] = cv[j2];
                    *(floatx4*)&outH2[base] = hv[j2];
                }
            }
            // re-stage this buffer with XW(s+2) (buffer freed: step-s compute done)
            stageXW(s + 2, s & 1);
        }
    }
}

extern "C" void kernel_launch(void* const* d_in, const int* in_sizes, int n_in,
                              void* d_out, int out_size, void* d_ws, size_t ws_size,
                              hipStream_t stream) {
    const float* inputs = (const float*)d_in[0];
    const void* terms = d_in[1];
    const float* c0 = (const float*)d_in[2];
    const float* h0 = (const float*)d_in[3];
    const float* Wx = (const float*)d_in[4];
    const float* Wh = (const float*)d_in[5];
    const float* bias = (const float*)d_in[6];
    float* out = (float*)d_out;

    size_t off = 0;
    auto take = [&](size_t bts) { size_t cur = off; off = (off + bts + 255) & ~(size_t)255; return cur; };
    size_t offXW = take((size_t)T_LEN * NC * 2);       // fp16 XW
    size_t offAin = take((size_t)T_LEN * DM * 2);
    size_t offPX = take((size_t)DM * NC * 2);
    size_t offPW = take((size_t)DM * NC * 2);
    size_t offSS = take((size_t)(T_LEN + 2) * 4);
    size_t offSL = take((size_t)(T_LEN + 2) * 4);
    size_t offH = take(2ull * NG * NR * DM * 2);
    size_t offFL = take((size_t)NG * WVG * 4);
    size_t offME = take(256);
    size_t total = off;
    (void)ws_size;

    char* W = (char*)d_ws;
    _Float16* Ain = (_Float16*)(W + offAin);
    half8* PX = (half8*)(W + offPX);
    half8* PWp = (half8*)(W + offPW);
    int* segS = (int*)(W + offSS);
    int* segL = (int*)(W + offSL);
    Meta* meta = (Meta*)(W + offME);
    _Float16* XWp = (_Float16*)(W + offXW);

    size_t zwords = (total - offH) / 4;  // Hbuf + flags + meta contiguous
    zero_kernel<<<256, 256, 0, stream>>>((u32*)(W + offH), zwords);
    pack_f16_kernel<<<(T_LEN * DM / 8 + 255) / 256, 256, 0, stream>>>(inputs, Ain, T_LEN * DM / 8);
    pack_w_kernel<<<512, 256, 0, stream>>>(Wx, PX);
    pack_w_kernel<<<512, 256, 0, stream>>>(Wh, PWp);
    prep_kernel<<<1, 256, 0, stream>>>(terms, h0, segS, segL, meta, (_Float16*)(W + offH));

    dim3 gg(T_LEN / 64, NC / 128);
    xw_gemm_kernel<<<gg, 256, 0, stream>>>((const half8*)Ain, (const half8*)PX, bias, XWp);
    scan_kernel<<<256, 192, 0, stream>>>((const half8*)PWp, XWp, c0, segS, segL, meta,
                                         (u64*)(W + offH), (int*)(W + offFL), out);
}